// Round 1
// baseline (2000.544 us; speedup 1.0000x reference)
//
#include <hip/hip_runtime.h>
#include <hip/hip_bf16.h>

#define B_  8
#define L_  2048
#define DM  512
#define DI  1024
#define DSs 16
#define T_  (B_*L_)        // 16384 tokens
#define EPSF 1e-5f

__device__ __forceinline__ float bf2f(unsigned short h){
    union { unsigned int u; float f; } v; v.u = ((unsigned int)h) << 16; return v.f;
}
__device__ __forceinline__ unsigned short f2bf(float f){
    union { float f; unsigned int u; } v; v.f = f;
    unsigned int r = v.u + 0x7fffu + ((v.u >> 16) & 1u);   // round-nearest-even
    return (unsigned short)(r >> 16);
}
__device__ __forceinline__ float sigmoidf_(float x){ return 1.f/(1.f+__expf(-x)); }

// ---------------------------------------------------------------- LayerNorm
// one wave per token row; outputs bf16 xn
__global__ void ln_kernel(const float* __restrict__ x, const float* __restrict__ w,
                          const float* __restrict__ b, unsigned short* __restrict__ xn){
    int row = blockIdx.x;
    int lane = threadIdx.x;                       // 0..63
    const float* xr = x + (size_t)row*DM;
    float v[8]; float s = 0.f, sq = 0.f;
    #pragma unroll
    for(int j=0;j<8;j++){ v[j] = xr[lane + 64*j]; s += v[j]; sq += v[j]*v[j]; }
    #pragma unroll
    for(int o=32;o>0;o>>=1){ s += __shfl_xor(s,o); sq += __shfl_xor(sq,o); }
    float mu  = s*(1.f/DM);
    float var = sq*(1.f/DM) - mu*mu;
    float rs  = rsqrtf(var + EPSF);
    unsigned short* out = xn + (size_t)row*DM;
    #pragma unroll
    for(int j=0;j<8;j++){
        int c = lane + 64*j;
        out[c] = f2bf((v[j]-mu)*rs*w[c] + b[c]);
    }
}

// ---------------------------------------------------------------- GEMM  C = A(bf16,[M,K],lda) * B(f32,[N,K])^T + bias
// OUTMODE 0: store bf16 (ldc stride); 1: store f32 + bias with col<N guard; 2: f32 + bias + residual
template<int OUTMODE>
__global__ void gemm_bt(const unsigned short* __restrict__ A, int lda,
                        const float* __restrict__ Bw, int N, int K,
                        const float* __restrict__ bias,
                        const float* __restrict__ resid,
                        void* __restrict__ Cout, int ldc)
{
    __shared__ __align__(16) float Ast[32][68];   // k-major, padded
    __shared__ __align__(16) float Bst[32][68];
    const int m0 = blockIdx.y * 64;
    const int n0 = blockIdx.x * 64;
    const int tid = threadIdx.x;
    const int ty = tid >> 4, tx = tid & 15;
    const int lrow = tid >> 2;            // 0..63
    const int lkb  = (tid & 3) * 8;       // 0,8,16,24
    float acc[4][4] = {{0.f}};

    for(int k0 = 0; k0 < K; k0 += 32){
        // A tile: 8 contiguous bf16 per thread (16B)
        {
            const unsigned short* ap = A + (size_t)(m0+lrow)*lda + k0 + lkb;
            uint4 pk = *reinterpret_cast<const uint4*>(ap);
            unsigned int uu[4] = {pk.x, pk.y, pk.z, pk.w};
            #pragma unroll
            for(int j=0;j<4;j++){
                Ast[lkb+2*j  ][lrow] = bf2f((unsigned short)(uu[j] & 0xffffu));
                Ast[lkb+2*j+1][lrow] = bf2f((unsigned short)(uu[j] >> 16));
            }
        }
        // B tile: 8 contiguous f32 per thread, zero-fill beyond N
        {
            int n = n0 + lrow;
            float4 f0 = {0,0,0,0}, f1 = {0,0,0,0};
            if(n < N){
                const float* bp = Bw + (size_t)n*K + k0 + lkb;
                f0 = *reinterpret_cast<const float4*>(bp);
                f1 = *reinterpret_cast<const float4*>(bp+4);
            }
            Bst[lkb+0][lrow]=f0.x; Bst[lkb+1][lrow]=f0.y; Bst[lkb+2][lrow]=f0.z; Bst[lkb+3][lrow]=f0.w;
            Bst[lkb+4][lrow]=f1.x; Bst[lkb+5][lrow]=f1.y; Bst[lkb+6][lrow]=f1.z; Bst[lkb+7][lrow]=f1.w;
        }
        __syncthreads();
        #pragma unroll
        for(int kk=0;kk<32;kk++){
            float4 a4 = *reinterpret_cast<const float4*>(&Ast[kk][ty*4]);
            float4 b4 = *reinterpret_cast<const float4*>(&Bst[kk][tx*4]);
            float av[4] = {a4.x,a4.y,a4.z,a4.w};
            float bv[4] = {b4.x,b4.y,b4.z,b4.w};
            #pragma unroll
            for(int i=0;i<4;i++)
                #pragma unroll
                for(int j=0;j<4;j++)
                    acc[i][j] += av[i]*bv[j];
        }
        __syncthreads();
    }

    if(OUTMODE == 0){
        unsigned short* C = (unsigned short*)Cout;
        #pragma unroll
        for(int i=0;i<4;i++){
            size_t r = (size_t)(m0 + ty*4 + i);
            int c = n0 + tx*4;
            unsigned int p0 = f2bf(acc[i][0]+bias[c+0]) | ((unsigned int)f2bf(acc[i][1]+bias[c+1])<<16);
            unsigned int p1 = f2bf(acc[i][2]+bias[c+2]) | ((unsigned int)f2bf(acc[i][3]+bias[c+3])<<16);
            uint2 pk = {p0, p1};
            *reinterpret_cast<uint2*>(C + r*ldc + c) = pk;
        }
    } else {
        float* C = (float*)Cout;
        #pragma unroll
        for(int i=0;i<4;i++){
            size_t r = (size_t)(m0 + ty*4 + i);
            int c = n0 + tx*4;
            #pragma unroll
            for(int j=0;j<4;j++){
                int cc = c + j;
                if(cc < N){
                    float vv = acc[i][j] + bias[cc];
                    if(OUTMODE == 2) vv += resid[r*(size_t)ldc + cc];
                    C[r*(size_t)ldc + cc] = vv;
                }
            }
        }
    }
}

// ---------------------------------------------------------------- depthwise conv3 + SiLU
// reads x_ half of xz (cols 0..1023), writes xs bf16 [T,1024]
__global__ void conv_silu_kernel(const unsigned short* __restrict__ xz,
                                 const float* __restrict__ cw, const float* __restrict__ cb,
                                 unsigned short* __restrict__ xs){
    int t = blockIdx.x;
    int l = t & (L_-1);
    int c = threadIdx.x * 4;
    const unsigned short* row = xz + (size_t)t*2048 + c;
    float cur[4], prv[4]={0,0,0,0}, nxt[4]={0,0,0,0};
    {
        uint2 u = *reinterpret_cast<const uint2*>(row);
        cur[0]=bf2f(u.x&0xffffu); cur[1]=bf2f(u.x>>16); cur[2]=bf2f(u.y&0xffffu); cur[3]=bf2f(u.y>>16);
    }
    if(l > 0){
        uint2 u = *reinterpret_cast<const uint2*>(row - 2048);
        prv[0]=bf2f(u.x&0xffffu); prv[1]=bf2f(u.x>>16); prv[2]=bf2f(u.y&0xffffu); prv[3]=bf2f(u.y>>16);
    }
    if(l < L_-1){
        uint2 u = *reinterpret_cast<const uint2*>(row + 2048);
        nxt[0]=bf2f(u.x&0xffffu); nxt[1]=bf2f(u.x>>16); nxt[2]=bf2f(u.y&0xffffu); nxt[3]=bf2f(u.y>>16);
    }
    unsigned short o[4];
    #pragma unroll
    for(int j=0;j<4;j++){
        int ch = c + j;
        float v = cw[ch*3+0]*prv[j] + cw[ch*3+1]*cur[j] + cw[ch*3+2]*nxt[j] + cb[ch];
        o[j] = f2bf(v * sigmoidf_(v));
    }
    unsigned int p0 = o[0] | ((unsigned int)o[1]<<16);
    unsigned int p1 = o[2] | ((unsigned int)o[3]<<16);
    uint2 pk = {p0,p1};
    *reinterpret_cast<uint2*>(xs + (size_t)t*1024 + c) = pk;
}

// ---------------------------------------------------------------- GRU scan (serial over L)
// 1 block x 128 threads: thread = (batch b = tid/16, state s = tid%16)
// h replicated per 16-lane group in registers; wave-synchronous shfl broadcast
__global__ void gru_kernel(const float* __restrict__ xg, const float* __restrict__ whh,
                           const float* __restrict__ bhh, float* __restrict__ y){
    int tid = threadIdx.x;
    int b = tid >> 4, s = tid & 15;
    float whr[16], whz[16], whn[16];
    #pragma unroll
    for(int k=0;k<16;k++){
        whr[k] = whh[(     s)*16 + k];
        whz[k] = whh[(16 + s)*16 + k];
        whn[k] = whh[(32 + s)*16 + k];
    }
    float br = bhh[s], bz = bhh[16+s], bn = bhh[32+s];
    float h[16];
    #pragma unroll
    for(int k=0;k<16;k++) h[k] = 0.f;
    float hself = 0.f;
    const float* xp = xg + (size_t)b*L_*48;
    float* yp = y + (size_t)b*L_*16;
    for(int t=0;t<L_;t++){
        float xr  = xp[t*48 +      s];
        float xzt = xp[t*48 + 16 + s];
        float xnn = xp[t*48 + 32 + s];
        float gr = br, gz = bz, gn = bn;
        #pragma unroll
        for(int k=0;k<16;k++){
            gr += whr[k]*h[k];
            gz += whz[k]*h[k];
            gn += whn[k]*h[k];
        }
        float r   = sigmoidf_(xr + gr);
        float zt  = sigmoidf_(xzt + gz);
        float pre = xnn + r*gn;
        float n   = 2.f*sigmoidf_(2.f*pre) - 1.f;    // tanh
        float hs  = (1.f - zt)*n + zt*hself;
        yp[t*16 + s] = hs;
        hself = hs;
        #pragma unroll
        for(int k=0;k<16;k++) h[k] = __shfl(hs, k, 16);
    }
}

// ---------------------------------------------------------------- ssm_proj + gate: g = (y @ ssm_w^T + sb) * silu(z)
// writes g (bf16) into the x_ half of xz (cols 0..1023)
__global__ void gated_kernel(const float* __restrict__ y, const float* __restrict__ sw,
                             const float* __restrict__ sb, unsigned short* __restrict__ xz){
    int t = blockIdx.x;
    __shared__ float ys[16];
    if(threadIdx.x < 16) ys[threadIdx.x] = y[(size_t)t*16 + threadIdx.x];
    __syncthreads();
    int e = threadIdx.x * 4;
    uint2 zz = *reinterpret_cast<const uint2*>(xz + (size_t)t*2048 + 1024 + e);
    float zv[4] = {bf2f(zz.x&0xffffu), bf2f(zz.x>>16), bf2f(zz.y&0xffffu), bf2f(zz.y>>16)};
    unsigned short o[4];
    #pragma unroll
    for(int j=0;j<4;j++){
        const float* wr = sw + (size_t)(e+j)*16;
        float a = sb[e+j];
        #pragma unroll
        for(int k=0;k<16;k++) a += wr[k]*ys[k];
        float sz = zv[j]*sigmoidf_(zv[j]);
        o[j] = f2bf(a*sz);
    }
    unsigned int p0 = o[0] | ((unsigned int)o[1]<<16);
    unsigned int p1 = o[2] | ((unsigned int)o[3]<<16);
    uint2 pk = {p0,p1};
    *reinterpret_cast<uint2*>(xz + (size_t)t*2048 + e) = pk;
}

// ---------------------------------------------------------------- launcher
extern "C" void kernel_launch(void* const* d_in, const int* in_sizes, int n_in,
                              void* d_out, int out_size, void* d_ws, size_t ws_size,
                              hipStream_t stream) {
    const float* x        = (const float*)d_in[0];
    const float* norm_w   = (const float*)d_in[1];
    const float* norm_b   = (const float*)d_in[2];
    const float* in_w     = (const float*)d_in[3];
    const float* in_b     = (const float*)d_in[4];
    const float* conv_w   = (const float*)d_in[5];
    const float* conv_b   = (const float*)d_in[6];
    const float* gih_w    = (const float*)d_in[7];
    const float* ghh_w    = (const float*)d_in[8];
    const float* gih_b    = (const float*)d_in[9];
    const float* ghh_b    = (const float*)d_in[10];
    const float* ssm_w    = (const float*)d_in[11];
    const float* ssm_b    = (const float*)d_in[12];
    const float* out_w    = (const float*)d_in[13];
    const float* out_b    = (const float*)d_in[14];
    float* out = (float*)d_out;

    char* w = (char*)d_ws;
    unsigned short* xn = (unsigned short*)(w);                         // T*512*2   = 16,777,216
    unsigned short* xz = (unsigned short*)(w + 16777216);              // T*2048*2  = 67,108,864
    unsigned short* xs = (unsigned short*)(w + 16777216 + 67108864);   // T*1024*2  = 33,554,432
    float*          xg = (float*)(w + 117440512);                      // T*48*4    = 3,145,728
    float*          yb = (float*)(w + 120586240);                      // T*16*4    = 1,048,576

    // 1. LayerNorm -> xn (bf16)
    ln_kernel<<<T_, 64, 0, stream>>>(x, norm_w, norm_b, xn);
    // 2. in_proj: xz[T,2048] = xn @ in_w^T + in_b   (bf16 out)
    gemm_bt<0><<<dim3(2048/64, T_/64), 256, 0, stream>>>(xn, DM, in_w, 2*DI, DM, in_b, nullptr, xz, 2*DI);
    // 3. depthwise conv3 + SiLU -> xs (bf16)
    conv_silu_kernel<<<T_, 256, 0, stream>>>(xz, conv_w, conv_b, xs);
    // 4. xg[T,48] = xs @ gih_w^T + gih_b   (f32 out)
    gemm_bt<1><<<dim3(1, T_/64), 256, 0, stream>>>(xs, DI, gih_w, 48, DI, gih_b, nullptr, xg, 48);
    // 5. GRU scan -> yb[T,16]
    gru_kernel<<<1, 128, 0, stream>>>(xg, ghh_w, ghh_b, yb);
    // 6. g = (yb @ ssm_w^T + ssm_b) * silu(z) -> bf16 into xz cols [0,1024)
    gated_kernel<<<T_, 256, 0, stream>>>(yb, ssm_w, ssm_b, xz);
    // 7. out = x + out_b + g @ out_w^T
    gemm_bt<2><<<dim3(DM/64, T_/64), 256, 0, stream>>>(xz, 2*DI, out_w, DM, DI, out_b, x, out, DM);
}

// Round 2
// 1529.149 us; speedup vs baseline: 1.3083x; 1.3083x over previous
//
#include <hip/hip_runtime.h>
#include <hip/hip_bf16.h>

#define B_  8
#define L_  2048
#define DM  512
#define DI  1024
#define DSs 16
#define T_  (B_*L_)        // 16384 tokens
#define EPSF 1e-5f

__device__ __forceinline__ float bf2f(unsigned short h){
    union { unsigned int u; float f; } v; v.u = ((unsigned int)h) << 16; return v.f;
}
__device__ __forceinline__ unsigned short f2bf(float f){
    union { float f; unsigned int u; } v; v.f = f;
    unsigned int r = v.u + 0x7fffu + ((v.u >> 16) & 1u);   // round-nearest-even
    return (unsigned short)(r >> 16);
}
__device__ __forceinline__ float sigmoidf_(float x){ return 1.f/(1.f+__expf(-x)); }

// ---------------------------------------------------------------- LayerNorm
// one wave per token row; outputs bf16 xn
__global__ void ln_kernel(const float* __restrict__ x, const float* __restrict__ w,
                          const float* __restrict__ b, unsigned short* __restrict__ xn){
    int row = blockIdx.x;
    int lane = threadIdx.x;                       // 0..63
    const float* xr = x + (size_t)row*DM;
    float v[8]; float s = 0.f, sq = 0.f;
    #pragma unroll
    for(int j=0;j<8;j++){ v[j] = xr[lane + 64*j]; s += v[j]; sq += v[j]*v[j]; }
    #pragma unroll
    for(int o=32;o>0;o>>=1){ s += __shfl_xor(s,o); sq += __shfl_xor(sq,o); }
    float mu  = s*(1.f/DM);
    float var = sq*(1.f/DM) - mu*mu;
    float rs  = rsqrtf(var + EPSF);
    unsigned short* out = xn + (size_t)row*DM;
    #pragma unroll
    for(int j=0;j<8;j++){
        int c = lane + 64*j;
        out[c] = f2bf((v[j]-mu)*rs*w[c] + b[c]);
    }
}

// ---------------------------------------------------------------- GEMM  C = A(bf16,[M,K],lda) * B(f32,[N,K])^T + bias
// OUTMODE 0: store bf16 (ldc stride); 1: store f32 + bias with col<N guard; 2: f32 + bias + residual
template<int OUTMODE>
__global__ void gemm_bt(const unsigned short* __restrict__ A, int lda,
                        const float* __restrict__ Bw, int N, int K,
                        const float* __restrict__ bias,
                        const float* __restrict__ resid,
                        void* __restrict__ Cout, int ldc)
{
    __shared__ __align__(16) float Ast[32][68];   // k-major, padded
    __shared__ __align__(16) float Bst[32][68];
    const int m0 = blockIdx.y * 64;
    const int n0 = blockIdx.x * 64;
    const int tid = threadIdx.x;
    const int ty = tid >> 4, tx = tid & 15;
    const int lrow = tid >> 2;            // 0..63
    const int lkb  = (tid & 3) * 8;       // 0,8,16,24
    float acc[4][4] = {{0.f}};

    for(int k0 = 0; k0 < K; k0 += 32){
        // A tile: 8 contiguous bf16 per thread (16B)
        {
            const unsigned short* ap = A + (size_t)(m0+lrow)*lda + k0 + lkb;
            uint4 pk = *reinterpret_cast<const uint4*>(ap);
            unsigned int uu[4] = {pk.x, pk.y, pk.z, pk.w};
            #pragma unroll
            for(int j=0;j<4;j++){
                Ast[lkb+2*j  ][lrow] = bf2f((unsigned short)(uu[j] & 0xffffu));
                Ast[lkb+2*j+1][lrow] = bf2f((unsigned short)(uu[j] >> 16));
            }
        }
        // B tile: 8 contiguous f32 per thread, zero-fill beyond N
        {
            int n = n0 + lrow;
            float4 f0 = {0,0,0,0}, f1 = {0,0,0,0};
            if(n < N){
                const float* bp = Bw + (size_t)n*K + k0 + lkb;
                f0 = *reinterpret_cast<const float4*>(bp);
                f1 = *reinterpret_cast<const float4*>(bp+4);
            }
            Bst[lkb+0][lrow]=f0.x; Bst[lkb+1][lrow]=f0.y; Bst[lkb+2][lrow]=f0.z; Bst[lkb+3][lrow]=f0.w;
            Bst[lkb+4][lrow]=f1.x; Bst[lkb+5][lrow]=f1.y; Bst[lkb+6][lrow]=f1.z; Bst[lkb+7][lrow]=f1.w;
        }
        __syncthreads();
        #pragma unroll
        for(int kk=0;kk<32;kk++){
            float4 a4 = *reinterpret_cast<const float4*>(&Ast[kk][ty*4]);
            float4 b4 = *reinterpret_cast<const float4*>(&Bst[kk][tx*4]);
            float av[4] = {a4.x,a4.y,a4.z,a4.w};
            float bv[4] = {b4.x,b4.y,b4.z,b4.w};
            #pragma unroll
            for(int i=0;i<4;i++)
                #pragma unroll
                for(int j=0;j<4;j++)
                    acc[i][j] += av[i]*bv[j];
        }
        __syncthreads();
    }

    if(OUTMODE == 0){
        unsigned short* C = (unsigned short*)Cout;
        #pragma unroll
        for(int i=0;i<4;i++){
            size_t r = (size_t)(m0 + ty*4 + i);
            int c = n0 + tx*4;
            unsigned int p0 = f2bf(acc[i][0]+bias[c+0]) | ((unsigned int)f2bf(acc[i][1]+bias[c+1])<<16);
            unsigned int p1 = f2bf(acc[i][2]+bias[c+2]) | ((unsigned int)f2bf(acc[i][3]+bias[c+3])<<16);
            uint2 pk = {p0, p1};
            *reinterpret_cast<uint2*>(C + r*ldc + c) = pk;
        }
    } else {
        float* C = (float*)Cout;
        #pragma unroll
        for(int i=0;i<4;i++){
            size_t r = (size_t)(m0 + ty*4 + i);
            int c = n0 + tx*4;
            #pragma unroll
            for(int j=0;j<4;j++){
                int cc = c + j;
                if(cc < N){
                    float vv = acc[i][j] + bias[cc];
                    if(OUTMODE == 2) vv += resid[r*(size_t)ldc + cc];
                    C[r*(size_t)ldc + cc] = vv;
                }
            }
        }
    }
}

// ---------------------------------------------------------------- depthwise conv3 + SiLU
// reads x_ half of xz (cols 0..1023), writes xs bf16 [T,1024]
__global__ void conv_silu_kernel(const unsigned short* __restrict__ xz,
                                 const float* __restrict__ cw, const float* __restrict__ cb,
                                 unsigned short* __restrict__ xs){
    int t = blockIdx.x;
    int l = t & (L_-1);
    int c = threadIdx.x * 4;
    const unsigned short* row = xz + (size_t)t*2048 + c;
    float cur[4], prv[4]={0,0,0,0}, nxt[4]={0,0,0,0};
    {
        uint2 u = *reinterpret_cast<const uint2*>(row);
        cur[0]=bf2f(u.x&0xffffu); cur[1]=bf2f(u.x>>16); cur[2]=bf2f(u.y&0xffffu); cur[3]=bf2f(u.y>>16);
    }
    if(l > 0){
        uint2 u = *reinterpret_cast<const uint2*>(row - 2048);
        prv[0]=bf2f(u.x&0xffffu); prv[1]=bf2f(u.x>>16); prv[2]=bf2f(u.y&0xffffu); prv[3]=bf2f(u.y>>16);
    }
    if(l < L_-1){
        uint2 u = *reinterpret_cast<const uint2*>(row + 2048);
        nxt[0]=bf2f(u.x&0xffffu); nxt[1]=bf2f(u.x>>16); nxt[2]=bf2f(u.y&0xffffu); nxt[3]=bf2f(u.y>>16);
    }
    unsigned short o[4];
    #pragma unroll
    for(int j=0;j<4;j++){
        int ch = c + j;
        float v = cw[ch*3+0]*prv[j] + cw[ch*3+1]*cur[j] + cw[ch*3+2]*nxt[j] + cb[ch];
        o[j] = f2bf(v * sigmoidf_(v));
    }
    unsigned int p0 = o[0] | ((unsigned int)o[1]<<16);
    unsigned int p1 = o[2] | ((unsigned int)o[3]<<16);
    uint2 pk = {p0,p1};
    *reinterpret_cast<uint2*>(xs + (size_t)t*1024 + c) = pk;
}

// ---------------------------------------------------------------- GRU scan (serial over L)
// 1 block x 128 threads: thread = (batch b = tid/16, state s = tid%16)
// h replicated per 16-lane group; xg loads software-pipelined 4 steps ahead
// so the serial chain is only: shfl-broadcast -> dot16 -> sigmoid -> tanh.
__global__ void gru_kernel(const float* __restrict__ xg, const float* __restrict__ whh,
                           const float* __restrict__ bhh, float* __restrict__ y){
    int tid = threadIdx.x;
    int b = tid >> 4, s = tid & 15;
    float whr[16], whz[16], whn[16];
    #pragma unroll
    for(int k=0;k<16;k++){
        whr[k] = whh[(     s)*16 + k];
        whz[k] = whh[(16 + s)*16 + k];
        whn[k] = whh[(32 + s)*16 + k];
    }
    float br = bhh[s], bz = bhh[16+s], bn = bhh[32+s];
    float h[16];
    #pragma unroll
    for(int k=0;k<16;k++) h[k] = 0.f;
    float hself = 0.f;
    const float* xp = xg + (size_t)b*L_*48 + s;
    float* yp = y + (size_t)b*L_*16 + s;

    // prefetch pipeline: distance 4, static register stages
    float cr[4], cz[4], cn[4];
    #pragma unroll
    for(int j=0;j<4;j++){
        cr[j] = xp[j*48]; cz[j] = xp[j*48+16]; cn[j] = xp[j*48+32];
    }
    for(int t=0;t<L_;t+=4){
        #pragma unroll
        for(int j=0;j<4;j++){
            // issue loads for step t+4+j first; first真 read is 4 steps later
            int ts = t+4+j; if(ts > L_-1) ts = L_-1;
            float pr = xp[ts*48], pz = xp[ts*48+16], pn = xp[ts*48+32];
            // ---- step t+j (serial chain) ----
            float gr=br, gz=bz, gn=bn;
            #pragma unroll
            for(int k=0;k<16;k++){ gr += whr[k]*h[k]; gz += whz[k]*h[k]; gn += whn[k]*h[k]; }
            float r   = sigmoidf_(cr[j] + gr);
            float zt  = sigmoidf_(cz[j] + gz);
            float pre = cn[j] + r*gn;
            float n   = 2.f*sigmoidf_(2.f*pre) - 1.f;    // tanh
            hself = (1.f - zt)*n + zt*hself;
            yp[(t+j)*16] = hself;
            #pragma unroll
            for(int k=0;k<16;k++) h[k] = __shfl(hself, k, 16);
            // ---- rotate pipeline ----
            cr[j]=pr; cz[j]=pz; cn[j]=pn;
        }
    }
}

// ---------------------------------------------------------------- ssm_proj + gate: g = (y @ ssm_w^T + sb) * silu(z)
// writes g (bf16) into the x_ half of xz (cols 0..1023)
__global__ void gated_kernel(const float* __restrict__ y, const float* __restrict__ sw,
                             const float* __restrict__ sb, unsigned short* __restrict__ xz){
    int t = blockIdx.x;
    __shared__ float ys[16];
    if(threadIdx.x < 16) ys[threadIdx.x] = y[(size_t)t*16 + threadIdx.x];
    __syncthreads();
    int e = threadIdx.x * 4;
    uint2 zz = *reinterpret_cast<const uint2*>(xz + (size_t)t*2048 + 1024 + e);
    float zv[4] = {bf2f(zz.x&0xffffu), bf2f(zz.x>>16), bf2f(zz.y&0xffffu), bf2f(zz.y>>16)};
    unsigned short o[4];
    #pragma unroll
    for(int j=0;j<4;j++){
        const float* wr = sw + (size_t)(e+j)*16;
        float a = sb[e+j];
        #pragma unroll
        for(int k=0;k<16;k++) a += wr[k]*ys[k];
        float sz = zv[j]*sigmoidf_(zv[j]);
        o[j] = f2bf(a*sz);
    }
    unsigned int p0 = o[0] | ((unsigned int)o[1]<<16);
    unsigned int p1 = o[2] | ((unsigned int)o[3]<<16);
    uint2 pk = {p0,p1};
    *reinterpret_cast<uint2*>(xz + (size_t)t*2048 + e) = pk;
}

// ---------------------------------------------------------------- launcher
extern "C" void kernel_launch(void* const* d_in, const int* in_sizes, int n_in,
                              void* d_out, int out_size, void* d_ws, size_t ws_size,
                              hipStream_t stream) {
    const float* x        = (const float*)d_in[0];
    const float* norm_w   = (const float*)d_in[1];
    const float* norm_b   = (const float*)d_in[2];
    const float* in_w     = (const float*)d_in[3];
    const float* in_b     = (const float*)d_in[4];
    const float* conv_w   = (const float*)d_in[5];
    const float* conv_b   = (const float*)d_in[6];
    const float* gih_w    = (const float*)d_in[7];
    const float* ghh_w    = (const float*)d_in[8];
    const float* gih_b    = (const float*)d_in[9];
    const float* ghh_b    = (const float*)d_in[10];
    const float* ssm_w    = (const float*)d_in[11];
    const float* ssm_b    = (const float*)d_in[12];
    const float* out_w    = (const float*)d_in[13];
    const float* out_b    = (const float*)d_in[14];
    float* out = (float*)d_out;

    char* w = (char*)d_ws;
    unsigned short* xn = (unsigned short*)(w);                         // T*512*2   = 16,777,216
    unsigned short* xz = (unsigned short*)(w + 16777216);              // T*2048*2  = 67,108,864
    unsigned short* xs = (unsigned short*)(w + 16777216 + 67108864);   // T*1024*2  = 33,554,432
    float*          xg = (float*)(w + 117440512);                      // T*48*4    = 3,145,728
    float*          yb = (float*)(w + 120586240);                      // T*16*4    = 1,048,576

    // 1. LayerNorm -> xn (bf16)
    ln_kernel<<<T_, 64, 0, stream>>>(x, norm_w, norm_b, xn);
    // 2. in_proj: xz[T,2048] = xn @ in_w^T + in_b   (bf16 out)
    gemm_bt<0><<<dim3(2048/64, T_/64), 256, 0, stream>>>(xn, DM, in_w, 2*DI, DM, in_b, nullptr, xz, 2*DI);
    // 3. depthwise conv3 + SiLU -> xs (bf16)
    conv_silu_kernel<<<T_, 256, 0, stream>>>(xz, conv_w, conv_b, xs);
    // 4. xg[T,48] = xs @ gih_w^T + gih_b   (f32 out)
    gemm_bt<1><<<dim3(1, T_/64), 256, 0, stream>>>(xs, DI, gih_w, 48, DI, gih_b, nullptr, xg, 48);
    // 5. GRU scan -> yb[T,16]
    gru_kernel<<<1, 128, 0, stream>>>(xg, ghh_w, ghh_b, yb);
    // 6. g = (yb @ ssm_w^T + ssm_b) * silu(z) -> bf16 into xz cols [0,1024)
    gated_kernel<<<T_, 256, 0, stream>>>(yb, ssm_w, ssm_b, xz);
    // 7. out = x + out_b + g @ out_w^T
    gemm_bt<2><<<dim3(DM/64, T_/64), 256, 0, stream>>>(xz, 2*DI, out_w, DM, DI, out_b, x, out, DM);
}

// Round 3
// 1529.057 us; speedup vs baseline: 1.3084x; 1.0001x over previous
//
#include <hip/hip_runtime.h>
#include <hip/hip_bf16.h>

#define B_  8
#define L_  2048
#define DM  512
#define DI  1024
#define DSs 16
#define T_  (B_*L_)        // 16384 tokens
#define EPSF 1e-5f

__device__ __forceinline__ float bf2f(unsigned short h){
    union { unsigned int u; float f; } v; v.u = ((unsigned int)h) << 16; return v.f;
}
__device__ __forceinline__ unsigned short f2bf(float f){
    union { float f; unsigned int u; } v; v.f = f;
    unsigned int r = v.u + 0x7fffu + ((v.u >> 16) & 1u);   // round-nearest-even
    return (unsigned short)(r >> 16);
}
__device__ __forceinline__ float sigmoidf_(float x){ return 1.f/(1.f+__expf(-x)); }

// ---------------------------------------------------------------- LayerNorm
// one wave per token row; outputs bf16 xn
__global__ void ln_kernel(const float* __restrict__ x, const float* __restrict__ w,
                          const float* __restrict__ b, unsigned short* __restrict__ xn){
    int row = blockIdx.x;
    int lane = threadIdx.x;                       // 0..63
    const float* xr = x + (size_t)row*DM;
    float v[8]; float s = 0.f, sq = 0.f;
    #pragma unroll
    for(int j=0;j<8;j++){ v[j] = xr[lane + 64*j]; s += v[j]; sq += v[j]*v[j]; }
    #pragma unroll
    for(int o=32;o>0;o>>=1){ s += __shfl_xor(s,o); sq += __shfl_xor(sq,o); }
    float mu  = s*(1.f/DM);
    float var = sq*(1.f/DM) - mu*mu;
    float rs  = rsqrtf(var + EPSF);
    unsigned short* out = xn + (size_t)row*DM;
    #pragma unroll
    for(int j=0;j<8;j++){
        int c = lane + 64*j;
        out[c] = f2bf((v[j]-mu)*rs*w[c] + b[c]);
    }
}

// ---------------------------------------------------------------- GEMM  C = A(bf16,[M,K],lda) * B(f32,[N,K])^T + bias
// OUTMODE 0: store bf16 (ldc stride); 1: store f32 + bias with col<N guard; 2: f32 + bias + residual
template<int OUTMODE>
__global__ void gemm_bt(const unsigned short* __restrict__ A, int lda,
                        const float* __restrict__ Bw, int N, int K,
                        const float* __restrict__ bias,
                        const float* __restrict__ resid,
                        void* __restrict__ Cout, int ldc)
{
    __shared__ __align__(16) float Ast[32][68];   // k-major, padded
    __shared__ __align__(16) float Bst[32][68];
    const int m0 = blockIdx.y * 64;
    const int n0 = blockIdx.x * 64;
    const int tid = threadIdx.x;
    const int ty = tid >> 4, tx = tid & 15;
    const int lrow = tid >> 2;            // 0..63
    const int lkb  = (tid & 3) * 8;       // 0,8,16,24
    float acc[4][4] = {{0.f}};

    for(int k0 = 0; k0 < K; k0 += 32){
        // A tile: 8 contiguous bf16 per thread (16B)
        {
            const unsigned short* ap = A + (size_t)(m0+lrow)*lda + k0 + lkb;
            uint4 pk = *reinterpret_cast<const uint4*>(ap);
            unsigned int uu[4] = {pk.x, pk.y, pk.z, pk.w};
            #pragma unroll
            for(int j=0;j<4;j++){
                Ast[lkb+2*j  ][lrow] = bf2f((unsigned short)(uu[j] & 0xffffu));
                Ast[lkb+2*j+1][lrow] = bf2f((unsigned short)(uu[j] >> 16));
            }
        }
        // B tile: 8 contiguous f32 per thread, zero-fill beyond N
        {
            int n = n0 + lrow;
            float4 f0 = {0,0,0,0}, f1 = {0,0,0,0};
            if(n < N){
                const float* bp = Bw + (size_t)n*K + k0 + lkb;
                f0 = *reinterpret_cast<const float4*>(bp);
                f1 = *reinterpret_cast<const float4*>(bp+4);
            }
            Bst[lkb+0][lrow]=f0.x; Bst[lkb+1][lrow]=f0.y; Bst[lkb+2][lrow]=f0.z; Bst[lkb+3][lrow]=f0.w;
            Bst[lkb+4][lrow]=f1.x; Bst[lkb+5][lrow]=f1.y; Bst[lkb+6][lrow]=f1.z; Bst[lkb+7][lrow]=f1.w;
        }
        __syncthreads();
        #pragma unroll
        for(int kk=0;kk<32;kk++){
            float4 a4 = *reinterpret_cast<const float4*>(&Ast[kk][ty*4]);
            float4 b4 = *reinterpret_cast<const float4*>(&Bst[kk][tx*4]);
            float av[4] = {a4.x,a4.y,a4.z,a4.w};
            float bv[4] = {b4.x,b4.y,b4.z,b4.w};
            #pragma unroll
            for(int i=0;i<4;i++)
                #pragma unroll
                for(int j=0;j<4;j++)
                    acc[i][j] += av[i]*bv[j];
        }
        __syncthreads();
    }

    if(OUTMODE == 0){
        unsigned short* C = (unsigned short*)Cout;
        #pragma unroll
        for(int i=0;i<4;i++){
            size_t r = (size_t)(m0 + ty*4 + i);
            int c = n0 + tx*4;
            unsigned int p0 = f2bf(acc[i][0]+bias[c+0]) | ((unsigned int)f2bf(acc[i][1]+bias[c+1])<<16);
            unsigned int p1 = f2bf(acc[i][2]+bias[c+2]) | ((unsigned int)f2bf(acc[i][3]+bias[c+3])<<16);
            uint2 pk = {p0, p1};
            *reinterpret_cast<uint2*>(C + r*ldc + c) = pk;
        }
    } else {
        float* C = (float*)Cout;
        #pragma unroll
        for(int i=0;i<4;i++){
            size_t r = (size_t)(m0 + ty*4 + i);
            int c = n0 + tx*4;
            #pragma unroll
            for(int j=0;j<4;j++){
                int cc = c + j;
                if(cc < N){
                    float vv = acc[i][j] + bias[cc];
                    if(OUTMODE == 2) vv += resid[r*(size_t)ldc + cc];
                    C[r*(size_t)ldc + cc] = vv;
                }
            }
        }
    }
}

// ---------------------------------------------------------------- depthwise conv3 + SiLU
// reads x_ half of xz (cols 0..1023), writes xs bf16 [T,1024]
__global__ void conv_silu_kernel(const unsigned short* __restrict__ xz,
                                 const float* __restrict__ cw, const float* __restrict__ cb,
                                 unsigned short* __restrict__ xs){
    int t = blockIdx.x;
    int l = t & (L_-1);
    int c = threadIdx.x * 4;
    const unsigned short* row = xz + (size_t)t*2048 + c;
    float cur[4], prv[4]={0,0,0,0}, nxt[4]={0,0,0,0};
    {
        uint2 u = *reinterpret_cast<const uint2*>(row);
        cur[0]=bf2f(u.x&0xffffu); cur[1]=bf2f(u.x>>16); cur[2]=bf2f(u.y&0xffffu); cur[3]=bf2f(u.y>>16);
    }
    if(l > 0){
        uint2 u = *reinterpret_cast<const uint2*>(row - 2048);
        prv[0]=bf2f(u.x&0xffffu); prv[1]=bf2f(u.x>>16); prv[2]=bf2f(u.y&0xffffu); prv[3]=bf2f(u.y>>16);
    }
    if(l < L_-1){
        uint2 u = *reinterpret_cast<const uint2*>(row + 2048);
        nxt[0]=bf2f(u.x&0xffffu); nxt[1]=bf2f(u.x>>16); nxt[2]=bf2f(u.y&0xffffu); nxt[3]=bf2f(u.y>>16);
    }
    unsigned short o[4];
    #pragma unroll
    for(int j=0;j<4;j++){
        int ch = c + j;
        float v = cw[ch*3+0]*prv[j] + cw[ch*3+1]*cur[j] + cw[ch*3+2]*nxt[j] + cb[ch];
        o[j] = f2bf(v * sigmoidf_(v));
    }
    unsigned int p0 = o[0] | ((unsigned int)o[1]<<16);
    unsigned int p1 = o[2] | ((unsigned int)o[3]<<16);
    uint2 pk = {p0,p1};
    *reinterpret_cast<uint2*>(xs + (size_t)t*1024 + c) = pk;
}

// ---------------------------------------------------------------- GRU scan (serial over L)
// 1 block x 128 threads: thread = (batch b = tid/16, state s = tid%16)
// h replicated per 16-lane group; xg loads software-pipelined 4 steps ahead
// so the serial chain is only: shfl-broadcast -> dot16 -> sigmoid -> tanh.
__global__ void gru_kernel(const float* __restrict__ xg, const float* __restrict__ whh,
                           const float* __restrict__ bhh, float* __restrict__ y){
    int tid = threadIdx.x;
    int b = tid >> 4, s = tid & 15;
    float whr[16], whz[16], whn[16];
    #pragma unroll
    for(int k=0;k<16;k++){
        whr[k] = whh[(     s)*16 + k];
        whz[k] = whh[(16 + s)*16 + k];
        whn[k] = whh[(32 + s)*16 + k];
    }
    float br = bhh[s], bz = bhh[16+s], bn = bhh[32+s];
    float h[16];
    #pragma unroll
    for(int k=0;k<16;k++) h[k] = 0.f;
    float hself = 0.f;
    const float* xp = xg + (size_t)b*L_*48 + s;
    float* yp = y + (size_t)b*L_*16 + s;

    // prefetch pipeline: distance 4, static register stages
    float cr[4], cz[4], cn[4];
    #pragma unroll
    for(int j=0;j<4;j++){
        cr[j] = xp[j*48]; cz[j] = xp[j*48+16]; cn[j] = xp[j*48+32];
    }
    for(int t=0;t<L_;t+=4){
        #pragma unroll
        for(int j=0;j<4;j++){
            // issue loads for step t+4+j first; first真 read is 4 steps later
            int ts = t+4+j; if(ts > L_-1) ts = L_-1;
            float pr = xp[ts*48], pz = xp[ts*48+16], pn = xp[ts*48+32];
            // ---- step t+j (serial chain) ----
            float gr=br, gz=bz, gn=bn;
            #pragma unroll
            for(int k=0;k<16;k++){ gr += whr[k]*h[k]; gz += whz[k]*h[k]; gn += whn[k]*h[k]; }
            float r   = sigmoidf_(cr[j] + gr);
            float zt  = sigmoidf_(cz[j] + gz);
            float pre = cn[j] + r*gn;
            float n   = 2.f*sigmoidf_(2.f*pre) - 1.f;    // tanh
            hself = (1.f - zt)*n + zt*hself;
            yp[(t+j)*16] = hself;
            #pragma unroll
            for(int k=0;k<16;k++) h[k] = __shfl(hself, k, 16);
            // ---- rotate pipeline ----
            cr[j]=pr; cz[j]=pz; cn[j]=pn;
        }
    }
}

// ---------------------------------------------------------------- ssm_proj + gate: g = (y @ ssm_w^T + sb) * silu(z)
// writes g (bf16) into the x_ half of xz (cols 0..1023)
__global__ void gated_kernel(const float* __restrict__ y, const float* __restrict__ sw,
                             const float* __restrict__ sb, unsigned short* __restrict__ xz){
    int t = blockIdx.x;
    __shared__ float ys[16];
    if(threadIdx.x < 16) ys[threadIdx.x] = y[(size_t)t*16 + threadIdx.x];
    __syncthreads();
    int e = threadIdx.x * 4;
    uint2 zz = *reinterpret_cast<const uint2*>(xz + (size_t)t*2048 + 1024 + e);
    float zv[4] = {bf2f(zz.x&0xffffu), bf2f(zz.x>>16), bf2f(zz.y&0xffffu), bf2f(zz.y>>16)};
    unsigned short o[4];
    #pragma unroll
    for(int j=0;j<4;j++){
        const float* wr = sw + (size_t)(e+j)*16;
        float a = sb[e+j];
        #pragma unroll
        for(int k=0;k<16;k++) a += wr[k]*ys[k];
        float sz = zv[j]*sigmoidf_(zv[j]);
        o[j] = f2bf(a*sz);
    }
    unsigned int p0 = o[0] | ((unsigned int)o[1]<<16);
    unsigned int p1 = o[2] | ((unsigned int)o[3]<<16);
    uint2 pk = {p0,p1};
    *reinterpret_cast<uint2*>(xz + (size_t)t*2048 + e) = pk;
}

// ---------------------------------------------------------------- launcher
extern "C" void kernel_launch(void* const* d_in, const int* in_sizes, int n_in,
                              void* d_out, int out_size, void* d_ws, size_t ws_size,
                              hipStream_t stream) {
    const float* x        = (const float*)d_in[0];
    const float* norm_w   = (const float*)d_in[1];
    const float* norm_b   = (const float*)d_in[2];
    const float* in_w     = (const float*)d_in[3];
    const float* in_b     = (const float*)d_in[4];
    const float* conv_w   = (const float*)d_in[5];
    const float* conv_b   = (const float*)d_in[6];
    const float* gih_w    = (const float*)d_in[7];
    const float* ghh_w    = (const float*)d_in[8];
    const float* gih_b    = (const float*)d_in[9];
    const float* ghh_b    = (const float*)d_in[10];
    const float* ssm_w    = (const float*)d_in[11];
    const float* ssm_b    = (const float*)d_in[12];
    const float* out_w    = (const float*)d_in[13];
    const float* out_b    = (const float*)d_in[14];
    float* out = (float*)d_out;

    char* w = (char*)d_ws;
    unsigned short* xn = (unsigned short*)(w);                         // T*512*2   = 16,777,216
    unsigned short* xz = (unsigned short*)(w + 16777216);              // T*2048*2  = 67,108,864
    unsigned short* xs = (unsigned short*)(w + 16777216 + 67108864);   // T*1024*2  = 33,554,432
    float*          xg = (float*)(w + 117440512);                      // T*48*4    = 3,145,728
    float*          yb = (float*)(w + 120586240);                      // T*16*4    = 1,048,576

    // 1. LayerNorm -> xn (bf16)
    ln_kernel<<<T_, 64, 0, stream>>>(x, norm_w, norm_b, xn);
    // 2. in_proj: xz[T,2048] = xn @ in_w^T + in_b   (bf16 out)
    gemm_bt<0><<<dim3(2048/64, T_/64), 256, 0, stream>>>(xn, DM, in_w, 2*DI, DM, in_b, nullptr, xz, 2*DI);
    // 3. depthwise conv3 + SiLU -> xs (bf16)
    conv_silu_kernel<<<T_, 256, 0, stream>>>(xz, conv_w, conv_b, xs);
    // 4. xg[T,48] = xs @ gih_w^T + gih_b   (f32 out)
    gemm_bt<1><<<dim3(1, T_/64), 256, 0, stream>>>(xs, DI, gih_w, 48, DI, gih_b, nullptr, xg, 48);
    // 5. GRU scan -> yb[T,16]
    gru_kernel<<<1, 128, 0, stream>>>(xg, ghh_w, ghh_b, yb);
    // 6. g = (yb @ ssm_w^T + ssm_b) * silu(z) -> bf16 into xz cols [0,1024)
    gated_kernel<<<T_, 256, 0, stream>>>(yb, ssm_w, ssm_b, xz);
    // 7. out = x + out_b + g @ out_w^T
    gemm_bt<2><<<dim3(DM/64, T_/64), 256, 0, stream>>>(xz, 2*DI, out_w, DM, DI, out_b, x, out, DM);
}

// Round 4
// 1496.941 us; speedup vs baseline: 1.3364x; 1.0215x over previous
//
#include <hip/hip_runtime.h>
#include <hip/hip_bf16.h>

#define B_  8
#define L_  2048
#define DM  512
#define DI  1024
#define DSs 16
#define T_  (B_*L_)        // 16384 tokens
#define EPSF 1e-5f

__device__ __forceinline__ float bf2f(unsigned short h){
    union { unsigned int u; float f; } v; v.u = ((unsigned int)h) << 16; return v.f;
}
__device__ __forceinline__ unsigned short f2bf(float f){
    union { float f; unsigned int u; } v; v.f = f;
    unsigned int r = v.u + 0x7fffu + ((v.u >> 16) & 1u);   // round-nearest-even
    return (unsigned short)(r >> 16);
}
__device__ __forceinline__ float sigmoidf_(float x){ return 1.f/(1.f+__expf(-x)); }

// DPP row-rotate (within 16-lane rows); CTRL: row_ror:N = 0x120+N
template<int CTRL>
__device__ __forceinline__ float dpp_rot(float x){
    int xi = __builtin_bit_cast(int, x);
    int r = __builtin_amdgcn_update_dpp(xi, xi, CTRL, 0xf, 0xf, false);
    return __builtin_bit_cast(float, r);
}

// ---------------------------------------------------------------- LayerNorm
// one wave per token row; outputs bf16 xn
__global__ void ln_kernel(const float* __restrict__ x, const float* __restrict__ w,
                          const float* __restrict__ b, unsigned short* __restrict__ xn){
    int row = blockIdx.x;
    int lane = threadIdx.x;                       // 0..63
    const float* xr = x + (size_t)row*DM;
    float v[8]; float s = 0.f, sq = 0.f;
    #pragma unroll
    for(int j=0;j<8;j++){ v[j] = xr[lane + 64*j]; s += v[j]; sq += v[j]*v[j]; }
    #pragma unroll
    for(int o=32;o>0;o>>=1){ s += __shfl_xor(s,o); sq += __shfl_xor(sq,o); }
    float mu  = s*(1.f/DM);
    float var = sq*(1.f/DM) - mu*mu;
    float rs  = rsqrtf(var + EPSF);
    unsigned short* out = xn + (size_t)row*DM;
    #pragma unroll
    for(int j=0;j<8;j++){
        int c = lane + 64*j;
        out[c] = f2bf((v[j]-mu)*rs*w[c] + b[c]);
    }
}

// ---------------------------------------------------------------- GEMM  C = A(bf16,[M,K],lda) * B(f32,[N,K])^T + bias
// OUTMODE 0: store bf16 (ldc stride); 1: store f32 + bias with col<N guard; 2: f32 + bias + residual
template<int OUTMODE>
__global__ void gemm_bt(const unsigned short* __restrict__ A, int lda,
                        const float* __restrict__ Bw, int N, int K,
                        const float* __restrict__ bias,
                        const float* __restrict__ resid,
                        void* __restrict__ Cout, int ldc)
{
    __shared__ __align__(16) float Ast[32][68];   // k-major, padded
    __shared__ __align__(16) float Bst[32][68];
    const int m0 = blockIdx.y * 64;
    const int n0 = blockIdx.x * 64;
    const int tid = threadIdx.x;
    const int ty = tid >> 4, tx = tid & 15;
    const int lrow = tid >> 2;            // 0..63
    const int lkb  = (tid & 3) * 8;       // 0,8,16,24
    float acc[4][4] = {{0.f}};

    for(int k0 = 0; k0 < K; k0 += 32){
        // A tile: 8 contiguous bf16 per thread (16B)
        {
            const unsigned short* ap = A + (size_t)(m0+lrow)*lda + k0 + lkb;
            uint4 pk = *reinterpret_cast<const uint4*>(ap);
            unsigned int uu[4] = {pk.x, pk.y, pk.z, pk.w};
            #pragma unroll
            for(int j=0;j<4;j++){
                Ast[lkb+2*j  ][lrow] = bf2f((unsigned short)(uu[j] & 0xffffu));
                Ast[lkb+2*j+1][lrow] = bf2f((unsigned short)(uu[j] >> 16));
            }
        }
        // B tile: 8 contiguous f32 per thread, zero-fill beyond N
        {
            int n = n0 + lrow;
            float4 f0 = {0,0,0,0}, f1 = {0,0,0,0};
            if(n < N){
                const float* bp = Bw + (size_t)n*K + k0 + lkb;
                f0 = *reinterpret_cast<const float4*>(bp);
                f1 = *reinterpret_cast<const float4*>(bp+4);
            }
            Bst[lkb+0][lrow]=f0.x; Bst[lkb+1][lrow]=f0.y; Bst[lkb+2][lrow]=f0.z; Bst[lkb+3][lrow]=f0.w;
            Bst[lkb+4][lrow]=f1.x; Bst[lkb+5][lrow]=f1.y; Bst[lkb+6][lrow]=f1.z; Bst[lkb+7][lrow]=f1.w;
        }
        __syncthreads();
        #pragma unroll
        for(int kk=0;kk<32;kk++){
            float4 a4 = *reinterpret_cast<const float4*>(&Ast[kk][ty*4]);
            float4 b4 = *reinterpret_cast<const float4*>(&Bst[kk][tx*4]);
            float av[4] = {a4.x,a4.y,a4.z,a4.w};
            float bv[4] = {b4.x,b4.y,b4.z,b4.w};
            #pragma unroll
            for(int i=0;i<4;i++)
                #pragma unroll
                for(int j=0;j<4;j++)
                    acc[i][j] += av[i]*bv[j];
        }
        __syncthreads();
    }

    if(OUTMODE == 0){
        unsigned short* C = (unsigned short*)Cout;
        #pragma unroll
        for(int i=0;i<4;i++){
            size_t r = (size_t)(m0 + ty*4 + i);
            int c = n0 + tx*4;
            unsigned int p0 = f2bf(acc[i][0]+bias[c+0]) | ((unsigned int)f2bf(acc[i][1]+bias[c+1])<<16);
            unsigned int p1 = f2bf(acc[i][2]+bias[c+2]) | ((unsigned int)f2bf(acc[i][3]+bias[c+3])<<16);
            uint2 pk = {p0, p1};
            *reinterpret_cast<uint2*>(C + r*ldc + c) = pk;
        }
    } else {
        float* C = (float*)Cout;
        #pragma unroll
        for(int i=0;i<4;i++){
            size_t r = (size_t)(m0 + ty*4 + i);
            int c = n0 + tx*4;
            #pragma unroll
            for(int j=0;j<4;j++){
                int cc = c + j;
                if(cc < N){
                    float vv = acc[i][j] + bias[cc];
                    if(OUTMODE == 2) vv += resid[r*(size_t)ldc + cc];
                    C[r*(size_t)ldc + cc] = vv;
                }
            }
        }
    }
}

// ---------------------------------------------------------------- depthwise conv3 + SiLU
// reads x_ half of xz (cols 0..1023), writes xs bf16 [T,1024]
__global__ void conv_silu_kernel(const unsigned short* __restrict__ xz,
                                 const float* __restrict__ cw, const float* __restrict__ cb,
                                 unsigned short* __restrict__ xs){
    int t = blockIdx.x;
    int l = t & (L_-1);
    int c = threadIdx.x * 4;
    const unsigned short* row = xz + (size_t)t*2048 + c;
    float cur[4], prv[4]={0,0,0,0}, nxt[4]={0,0,0,0};
    {
        uint2 u = *reinterpret_cast<const uint2*>(row);
        cur[0]=bf2f(u.x&0xffffu); cur[1]=bf2f(u.x>>16); cur[2]=bf2f(u.y&0xffffu); cur[3]=bf2f(u.y>>16);
    }
    if(l > 0){
        uint2 u = *reinterpret_cast<const uint2*>(row - 2048);
        prv[0]=bf2f(u.x&0xffffu); prv[1]=bf2f(u.x>>16); prv[2]=bf2f(u.y&0xffffu); prv[3]=bf2f(u.y>>16);
    }
    if(l < L_-1){
        uint2 u = *reinterpret_cast<const uint2*>(row + 2048);
        nxt[0]=bf2f(u.x&0xffffu); nxt[1]=bf2f(u.x>>16); nxt[2]=bf2f(u.y&0xffffu); nxt[3]=bf2f(u.y>>16);
    }
    unsigned short o[4];
    #pragma unroll
    for(int j=0;j<4;j++){
        int ch = c + j;
        float v = cw[ch*3+0]*prv[j] + cw[ch*3+1]*cur[j] + cw[ch*3+2]*nxt[j] + cb[ch];
        o[j] = f2bf(v * sigmoidf_(v));
    }
    unsigned int p0 = o[0] | ((unsigned int)o[1]<<16);
    unsigned int p1 = o[2] | ((unsigned int)o[3]<<16);
    uint2 pk = {p0,p1};
    *reinterpret_cast<uint2*>(xs + (size_t)t*1024 + c) = pk;
}

// ---------------------------------------------------------------- GRU scan (serial over L)
// 1 block x 128 threads: thread = (batch b = tid/16, state s = tid%16).
// Lane s holds ONLY h[s]. The 16x16 matvec is computed systolically:
// h values rotate around the 16-lane row via DPP row_ror (pure VALU, no LDS),
// weights preloaded row-permuted. Two interleaved ror:2 chains (depth 8).
// DPP direction is resolved at runtime with a 2-instr self-check (deterministic).
__global__ void gru_kernel(const float* __restrict__ xg, const float* __restrict__ whh,
                           const float* __restrict__ bhh, float* __restrict__ y){
    int tid = threadIdx.x;
    int b = tid >> 4, s = tid & 15;
    // direction self-check: after ror:1, lane s holds marker of lane (s+dir)&15
    int mk = __builtin_amdgcn_update_dpp(s, s, 0x121, 0xf, 0xf, false);
    int dir = (mk == ((s+15)&15)) ? 15 : 1;      // 15 ≡ -1 (mod 16)
    // preload permuted weights: chain A sees h[(s+2m*dir)&15], chain B h[(s+(2m+1)*dir)&15]
    float wr[2][8], wz[2][8], wn[2][8];
    #pragma unroll
    for(int m=0;m<8;m++){
        int jA = (s + 2*m*dir) & 15;
        int jB = (s + (2*m+1)*dir) & 15;
        wr[0][m] = whh[(     s)*16 + jA]; wr[1][m] = whh[(     s)*16 + jB];
        wz[0][m] = whh[(16 + s)*16 + jA]; wz[1][m] = whh[(16 + s)*16 + jB];
        wn[0][m] = whh[(32 + s)*16 + jA]; wn[1][m] = whh[(32 + s)*16 + jB];
    }
    float br = bhh[s], bz = bhh[16+s], bn = bhh[32+s];
    float hself = 0.f;
    const float* xp = xg + (size_t)b*L_*48 + s;
    float* yp = y + (size_t)b*L_*16 + s;

    // prefetch pipeline: distance 4, static register stages
    float cr[4], cz[4], cn[4];
    #pragma unroll
    for(int j=0;j<4;j++){
        cr[j] = xp[j*48]; cz[j] = xp[j*48+16]; cn[j] = xp[j*48+32];
    }
    for(int t=0;t<L_;t+=4){
        #pragma unroll
        for(int j=0;j<4;j++){
            // issue loads for step t+4+j first; first read of them is 4 steps later
            int ts = t+4+j; if(ts > L_-1) ts = L_-1;
            float pr = xp[ts*48], pz = xp[ts*48+16], pn = xp[ts*48+32];
            // ---- step t+j: systolic matvec over rotating h ----
            float hrA = hself;
            float hrB = dpp_rot<0x121>(hself);    // ror:1
            float grA=0.f,gzA=0.f,gnA=0.f, grB=0.f,gzB=0.f,gnB=0.f;
            #pragma unroll
            for(int m=0;m<8;m++){
                grA += wr[0][m]*hrA; gzA += wz[0][m]*hrA; gnA += wn[0][m]*hrA;
                grB += wr[1][m]*hrB; gzB += wz[1][m]*hrB; gnB += wn[1][m]*hrB;
                if(m<7){ hrA = dpp_rot<0x122>(hrA); hrB = dpp_rot<0x122>(hrB); }  // ror:2
            }
            float gr = br + grA + grB;
            float gz = bz + gzA + gzB;
            float gn = bn + gnA + gnB;
            float r   = sigmoidf_(cr[j] + gr);
            float zt  = sigmoidf_(cz[j] + gz);
            float pre = cn[j] + r*gn;
            float n   = 2.f*sigmoidf_(2.f*pre) - 1.f;    // tanh
            hself = (1.f - zt)*n + zt*hself;
            yp[(t+j)*16] = hself;
            // ---- rotate prefetch pipeline ----
            cr[j]=pr; cz[j]=pz; cn[j]=pn;
        }
    }
}

// ---------------------------------------------------------------- ssm_proj + gate: g = (y @ ssm_w^T + sb) * silu(z)
// writes g (bf16) into the x_ half of xz (cols 0..1023)
__global__ void gated_kernel(const float* __restrict__ y, const float* __restrict__ sw,
                             const float* __restrict__ sb, unsigned short* __restrict__ xz){
    int t = blockIdx.x;
    __shared__ float ys[16];
    if(threadIdx.x < 16) ys[threadIdx.x] = y[(size_t)t*16 + threadIdx.x];
    __syncthreads();
    int e = threadIdx.x * 4;
    uint2 zz = *reinterpret_cast<const uint2*>(xz + (size_t)t*2048 + 1024 + e);
    float zv[4] = {bf2f(zz.x&0xffffu), bf2f(zz.x>>16), bf2f(zz.y&0xffffu), bf2f(zz.y>>16)};
    unsigned short o[4];
    #pragma unroll
    for(int j=0;j<4;j++){
        const float* wr = sw + (size_t)(e+j)*16;
        float a = sb[e+j];
        #pragma unroll
        for(int k=0;k<16;k++) a += wr[k]*ys[k];
        float sz = zv[j]*sigmoidf_(zv[j]);
        o[j] = f2bf(a*sz);
    }
    unsigned int p0 = o[0] | ((unsigned int)o[1]<<16);
    unsigned int p1 = o[2] | ((unsigned int)o[3]<<16);
    uint2 pk = {p0,p1};
    *reinterpret_cast<uint2*>(xz + (size_t)t*2048 + e) = pk;
}

// ---------------------------------------------------------------- launcher
extern "C" void kernel_launch(void* const* d_in, const int* in_sizes, int n_in,
                              void* d_out, int out_size, void* d_ws, size_t ws_size,
                              hipStream_t stream) {
    const float* x        = (const float*)d_in[0];
    const float* norm_w   = (const float*)d_in[1];
    const float* norm_b   = (const float*)d_in[2];
    const float* in_w     = (const float*)d_in[3];
    const float* in_b     = (const float*)d_in[4];
    const float* conv_w   = (const float*)d_in[5];
    const float* conv_b   = (const float*)d_in[6];
    const float* gih_w    = (const float*)d_in[7];
    const float* ghh_w    = (const float*)d_in[8];
    const float* gih_b    = (const float*)d_in[9];
    const float* ghh_b    = (const float*)d_in[10];
    const float* ssm_w    = (const float*)d_in[11];
    const float* ssm_b    = (const float*)d_in[12];
    const float* out_w    = (const float*)d_in[13];
    const float* out_b    = (const float*)d_in[14];
    float* out = (float*)d_out;

    char* w = (char*)d_ws;
    unsigned short* xn = (unsigned short*)(w);                         // T*512*2   = 16,777,216
    unsigned short* xz = (unsigned short*)(w + 16777216);              // T*2048*2  = 67,108,864
    unsigned short* xs = (unsigned short*)(w + 16777216 + 67108864);   // T*1024*2  = 33,554,432
    float*          xg = (float*)(w + 117440512);                      // T*48*4    = 3,145,728
    float*          yb = (float*)(w + 120586240);                      // T*16*4    = 1,048,576

    // 1. LayerNorm -> xn (bf16)
    ln_kernel<<<T_, 64, 0, stream>>>(x, norm_w, norm_b, xn);
    // 2. in_proj: xz[T,2048] = xn @ in_w^T + in_b   (bf16 out)
    gemm_bt<0><<<dim3(2048/64, T_/64), 256, 0, stream>>>(xn, DM, in_w, 2*DI, DM, in_b, nullptr, xz, 2*DI);
    // 3. depthwise conv3 + SiLU -> xs (bf16)
    conv_silu_kernel<<<T_, 256, 0, stream>>>(xz, conv_w, conv_b, xs);
    // 4. xg[T,48] = xs @ gih_w^T + gih_b   (f32 out)
    gemm_bt<1><<<dim3(1, T_/64), 256, 0, stream>>>(xs, DI, gih_w, 48, DI, gih_b, nullptr, xg, 48);
    // 5. GRU scan -> yb[T,16]
    gru_kernel<<<1, 128, 0, stream>>>(xg, ghh_w, ghh_b, yb);
    // 6. g = (yb @ ssm_w^T + ssm_b) * silu(z) -> bf16 into xz cols [0,1024)
    gated_kernel<<<T_, 256, 0, stream>>>(yb, ssm_w, ssm_b, xz);
    // 7. out = x + out_b + g @ out_w^T
    gemm_bt<2><<<dim3(DM/64, T_/64), 256, 0, stream>>>(xz, 2*DI, out_w, DM, DI, out_b, x, out, DM);
}

// Round 5
// 1343.479 us; speedup vs baseline: 1.4891x; 1.1142x over previous
//
#include <hip/hip_runtime.h>
#include <hip/hip_bf16.h>

#define B_  8
#define L_  2048
#define DM  512
#define DI  1024
#define DSs 16
#define T_  (B_*L_)        // 16384 tokens
#define EPSF 1e-5f

__device__ __forceinline__ float bf2f(unsigned short h){
    union { unsigned int u; float f; } v; v.u = ((unsigned int)h) << 16; return v.f;
}
__device__ __forceinline__ unsigned short f2bf(float f){
    union { float f; unsigned int u; } v; v.f = f;
    unsigned int r = v.u + 0x7fffu + ((v.u >> 16) & 1u);   // round-nearest-even
    return (unsigned short)(r >> 16);
}
__device__ __forceinline__ float sigmoidf_(float x){ return 1.f/(1.f+__expf(-x)); }

// DPP row-rotate (within 16-lane rows); CTRL: row_ror:N = 0x120+N
template<int CTRL>
__device__ __forceinline__ float dpp_rot(float x){
    int xi = __builtin_bit_cast(int, x);
    int r = __builtin_amdgcn_update_dpp(xi, xi, CTRL, 0xf, 0xf, false);
    return __builtin_bit_cast(float, r);
}

// ---------------------------------------------------------------- LayerNorm
// one wave per token row; outputs bf16 xn
__global__ void ln_kernel(const float* __restrict__ x, const float* __restrict__ w,
                          const float* __restrict__ b, unsigned short* __restrict__ xn){
    int row = blockIdx.x;
    int lane = threadIdx.x;                       // 0..63
    const float* xr = x + (size_t)row*DM;
    float v[8]; float s = 0.f, sq = 0.f;
    #pragma unroll
    for(int j=0;j<8;j++){ v[j] = xr[lane + 64*j]; s += v[j]; sq += v[j]*v[j]; }
    #pragma unroll
    for(int o=32;o>0;o>>=1){ s += __shfl_xor(s,o); sq += __shfl_xor(sq,o); }
    float mu  = s*(1.f/DM);
    float var = sq*(1.f/DM) - mu*mu;
    float rs  = rsqrtf(var + EPSF);
    unsigned short* out = xn + (size_t)row*DM;
    #pragma unroll
    for(int j=0;j<8;j++){
        int c = lane + 64*j;
        out[c] = f2bf((v[j]-mu)*rs*w[c] + b[c]);
    }
}

// ---------------------------------------------------------------- GEMM  C = A(bf16,[M,K],lda) * B(f32,[N,K])^T + bias
// OUTMODE 0: store bf16 (ldc stride); 1: f32 + bias, col<N guard; 2: f32 + bias + residual;
// OUTMODE 3: f32 + bias, TRANSPOSED store to [8][N][2048] (token r -> (b = r>>11, l = r&2047))
template<int OUTMODE>
__global__ void gemm_bt(const unsigned short* __restrict__ A, int lda,
                        const float* __restrict__ Bw, int N, int K,
                        const float* __restrict__ bias,
                        const float* __restrict__ resid,
                        void* __restrict__ Cout, int ldc)
{
    __shared__ __align__(16) float Ast[32][68];   // k-major, padded
    __shared__ __align__(16) float Bst[32][68];
    const int m0 = blockIdx.y * 64;
    const int n0 = blockIdx.x * 64;
    const int tid = threadIdx.x;
    const int ty = tid >> 4, tx = tid & 15;
    const int lrow = tid >> 2;            // 0..63
    const int lkb  = (tid & 3) * 8;       // 0,8,16,24
    float acc[4][4] = {{0.f}};

    for(int k0 = 0; k0 < K; k0 += 32){
        // A tile: 8 contiguous bf16 per thread (16B)
        {
            const unsigned short* ap = A + (size_t)(m0+lrow)*lda + k0 + lkb;
            uint4 pk = *reinterpret_cast<const uint4*>(ap);
            unsigned int uu[4] = {pk.x, pk.y, pk.z, pk.w};
            #pragma unroll
            for(int j=0;j<4;j++){
                Ast[lkb+2*j  ][lrow] = bf2f((unsigned short)(uu[j] & 0xffffu));
                Ast[lkb+2*j+1][lrow] = bf2f((unsigned short)(uu[j] >> 16));
            }
        }
        // B tile: 8 contiguous f32 per thread, zero-fill beyond N
        {
            int n = n0 + lrow;
            float4 f0 = {0,0,0,0}, f1 = {0,0,0,0};
            if(n < N){
                const float* bp = Bw + (size_t)n*K + k0 + lkb;
                f0 = *reinterpret_cast<const float4*>(bp);
                f1 = *reinterpret_cast<const float4*>(bp+4);
            }
            Bst[lkb+0][lrow]=f0.x; Bst[lkb+1][lrow]=f0.y; Bst[lkb+2][lrow]=f0.z; Bst[lkb+3][lrow]=f0.w;
            Bst[lkb+4][lrow]=f1.x; Bst[lkb+5][lrow]=f1.y; Bst[lkb+6][lrow]=f1.z; Bst[lkb+7][lrow]=f1.w;
        }
        __syncthreads();
        #pragma unroll
        for(int kk=0;kk<32;kk++){
            float4 a4 = *reinterpret_cast<const float4*>(&Ast[kk][ty*4]);
            float4 b4 = *reinterpret_cast<const float4*>(&Bst[kk][tx*4]);
            float av[4] = {a4.x,a4.y,a4.z,a4.w};
            float bv[4] = {b4.x,b4.y,b4.z,b4.w};
            #pragma unroll
            for(int i=0;i<4;i++)
                #pragma unroll
                for(int j=0;j<4;j++)
                    acc[i][j] += av[i]*bv[j];
        }
        __syncthreads();
    }

    if(OUTMODE == 0){
        unsigned short* C = (unsigned short*)Cout;
        #pragma unroll
        for(int i=0;i<4;i++){
            size_t r = (size_t)(m0 + ty*4 + i);
            int c = n0 + tx*4;
            unsigned int p0 = f2bf(acc[i][0]+bias[c+0]) | ((unsigned int)f2bf(acc[i][1]+bias[c+1])<<16);
            unsigned int p1 = f2bf(acc[i][2]+bias[c+2]) | ((unsigned int)f2bf(acc[i][3]+bias[c+3])<<16);
            uint2 pk = {p0, p1};
            *reinterpret_cast<uint2*>(C + r*ldc + c) = pk;
        }
    } else if(OUTMODE == 3){
        float* C = (float*)Cout;   // [8][N][2048]
        #pragma unroll
        for(int i=0;i<4;i++){
            size_t r = (size_t)(m0 + ty*4 + i);
            size_t bb = r >> 11, ll = r & 2047;
            int c = n0 + tx*4;
            #pragma unroll
            for(int j=0;j<4;j++){
                int cc = c + j;
                if(cc < N) C[(bb*(size_t)N + cc)*2048 + ll] = acc[i][j] + bias[cc];
            }
        }
    } else {
        float* C = (float*)Cout;
        #pragma unroll
        for(int i=0;i<4;i++){
            size_t r = (size_t)(m0 + ty*4 + i);
            int c = n0 + tx*4;
            #pragma unroll
            for(int j=0;j<4;j++){
                int cc = c + j;
                if(cc < N){
                    float vv = acc[i][j] + bias[cc];
                    if(OUTMODE == 2) vv += resid[r*(size_t)ldc + cc];
                    C[r*(size_t)ldc + cc] = vv;
                }
            }
        }
    }
}

// ---------------------------------------------------------------- depthwise conv3 + SiLU
// reads x_ half of xz (cols 0..1023), writes xs bf16 [T,1024]
__global__ void conv_silu_kernel(const unsigned short* __restrict__ xz,
                                 const float* __restrict__ cw, const float* __restrict__ cb,
                                 unsigned short* __restrict__ xs){
    int t = blockIdx.x;
    int l = t & (L_-1);
    int c = threadIdx.x * 4;
    const unsigned short* row = xz + (size_t)t*2048 + c;
    float cur[4], prv[4]={0,0,0,0}, nxt[4]={0,0,0,0};
    {
        uint2 u = *reinterpret_cast<const uint2*>(row);
        cur[0]=bf2f(u.x&0xffffu); cur[1]=bf2f(u.x>>16); cur[2]=bf2f(u.y&0xffffu); cur[3]=bf2f(u.y>>16);
    }
    if(l > 0){
        uint2 u = *reinterpret_cast<const uint2*>(row - 2048);
        prv[0]=bf2f(u.x&0xffffu); prv[1]=bf2f(u.x>>16); prv[2]=bf2f(u.y&0xffffu); prv[3]=bf2f(u.y>>16);
    }
    if(l < L_-1){
        uint2 u = *reinterpret_cast<const uint2*>(row + 2048);
        nxt[0]=bf2f(u.x&0xffffu); nxt[1]=bf2f(u.x>>16); nxt[2]=bf2f(u.y&0xffffu); nxt[3]=bf2f(u.y>>16);
    }
    unsigned short o[4];
    #pragma unroll
    for(int j=0;j<4;j++){
        int ch = c + j;
        float v = cw[ch*3+0]*prv[j] + cw[ch*3+1]*cur[j] + cw[ch*3+2]*nxt[j] + cb[ch];
        o[j] = f2bf(v * sigmoidf_(v));
    }
    unsigned int p0 = o[0] | ((unsigned int)o[1]<<16);
    unsigned int p1 = o[2] | ((unsigned int)o[3]<<16);
    uint2 pk = {p0,p1};
    *reinterpret_cast<uint2*>(xs + (size_t)t*1024 + c) = pk;
}

// ---------------------------------------------------------------- GRU scan (serial over L)
// 1 block x 128 threads: thread = (batch b = tid/16, state s = tid%16).
// xg is TRANSPOSED [8][48][2048]: lane s streams its 3 gate rows contiguously in t.
// One float4 load covers 4 steps of one gate; 4-group (16-step) static register
// pipeline keeps 12 loads in flight (covers ~HBM latency). DPP systolic matvec.
__global__ void gru_kernel(const float* __restrict__ xgT, const float* __restrict__ whh,
                           const float* __restrict__ bhh, float* __restrict__ yT){
    int tid = threadIdx.x;
    int b = tid >> 4, s = tid & 15;
    // DPP direction self-check (deterministic)
    int mk = __builtin_amdgcn_update_dpp(s, s, 0x121, 0xf, 0xf, false);
    int dir = (mk == ((s+15)&15)) ? 15 : 1;      // 15 ≡ -1 (mod 16)
    float wr[2][8], wz[2][8], wn[2][8];
    #pragma unroll
    for(int m=0;m<8;m++){
        int jA = (s + 2*m*dir) & 15;
        int jB = (s + (2*m+1)*dir) & 15;
        wr[0][m] = whh[(     s)*16 + jA]; wr[1][m] = whh[(     s)*16 + jB];
        wz[0][m] = whh[(16 + s)*16 + jA]; wz[1][m] = whh[(16 + s)*16 + jB];
        wn[0][m] = whh[(32 + s)*16 + jA]; wn[1][m] = whh[(32 + s)*16 + jB];
    }
    float br = bhh[s], bz = bhh[16+s], bn = bhh[32+s];
    const float* xr_ = xgT + ((size_t)b*48 +      s)*L_;
    const float* xz_ = xgT + ((size_t)b*48 + 16 + s)*L_;
    const float* xn_ = xgT + ((size_t)b*48 + 32 + s)*L_;
    float* yp = yT + ((size_t)b*16 + s)*L_;

    union F4 { float4 v; float a[4]; };
    F4 fr[4], fz[4], fn[4];
    #pragma unroll
    for(int g=0; g<4; g++){
        fr[g].v = *reinterpret_cast<const float4*>(xr_ + g*4);
        fz[g].v = *reinterpret_cast<const float4*>(xz_ + g*4);
        fn[g].v = *reinterpret_cast<const float4*>(xn_ + g*4);
    }
    float hself = 0.f;
    for(int tg=0; tg<512; tg+=4){
        #pragma unroll
        for(int q=0;q<4;q++){
            // issue prefetch for group tg+q+4 (consumed 16 steps later)
            int nx = tg + q + 4; if(nx > 511) nx = 511;
            float4 pr = *reinterpret_cast<const float4*>(xr_ + nx*4);
            float4 pz = *reinterpret_cast<const float4*>(xz_ + nx*4);
            float4 pn = *reinterpret_cast<const float4*>(xn_ + nx*4);
            F4 ho;
            #pragma unroll
            for(int j=0;j<4;j++){
                // systolic matvec over rotating h (pure VALU)
                float hrA = hself;
                float hrB = dpp_rot<0x121>(hself);    // ror:1
                float grA=0.f,gzA=0.f,gnA=0.f, grB=0.f,gzB=0.f,gnB=0.f;
                #pragma unroll
                for(int m=0;m<8;m++){
                    grA += wr[0][m]*hrA; gzA += wz[0][m]*hrA; gnA += wn[0][m]*hrA;
                    grB += wr[1][m]*hrB; gzB += wz[1][m]*hrB; gnB += wn[1][m]*hrB;
                    if(m<7){ hrA = dpp_rot<0x122>(hrA); hrB = dpp_rot<0x122>(hrB); }  // ror:2
                }
                float r   = sigmoidf_(fr[q].a[j] + br + grA + grB);
                float zt  = sigmoidf_(fz[q].a[j] + bz + gzA + gzB);
                float gn  = bn + gnA + gnB;
                float pre = fn[q].a[j] + r*gn;
                float n   = 2.f*sigmoidf_(2.f*pre) - 1.f;    // tanh
                hself = (1.f - zt)*n + zt*hself;
                ho.a[j] = hself;
            }
            *reinterpret_cast<float4*>(yp + (size_t)(tg+q)*4) = ho.v;
            fr[q].v = pr; fz[q].v = pz; fn[q].v = pn;
        }
    }
}

// ---------------------------------------------------------------- ssm_proj + gate: g = (y @ ssm_w^T + sb) * silu(z)
// y is transposed [8][16][2048]; writes g (bf16) into the x_ half of xz (cols 0..1023)
__global__ void gated_kernel(const float* __restrict__ yT, const float* __restrict__ sw,
                             const float* __restrict__ sb, unsigned short* __restrict__ xz){
    int t = blockIdx.x;
    int bb = t >> 11, ll = t & 2047;
    __shared__ float ys[16];
    if(threadIdx.x < 16) ys[threadIdx.x] = yT[((size_t)bb*16 + threadIdx.x)*L_ + ll];
    __syncthreads();
    int e = threadIdx.x * 4;
    uint2 zz = *reinterpret_cast<const uint2*>(xz + (size_t)t*2048 + 1024 + e);
    float zv[4] = {bf2f(zz.x&0xffffu), bf2f(zz.x>>16), bf2f(zz.y&0xffffu), bf2f(zz.y>>16)};
    unsigned short o[4];
    #pragma unroll
    for(int j=0;j<4;j++){
        const float* wrow = sw + (size_t)(e+j)*16;
        float a = sb[e+j];
        #pragma unroll
        for(int k=0;k<16;k++) a += wrow[k]*ys[k];
        float sz = zv[j]*sigmoidf_(zv[j]);
        o[j] = f2bf(a*sz);
    }
    unsigned int p0 = o[0] | ((unsigned int)o[1]<<16);
    unsigned int p1 = o[2] | ((unsigned int)o[3]<<16);
    uint2 pk = {p0,p1};
    *reinterpret_cast<uint2*>(xz + (size_t)t*2048 + e) = pk;
}

// ---------------------------------------------------------------- launcher
extern "C" void kernel_launch(void* const* d_in, const int* in_sizes, int n_in,
                              void* d_out, int out_size, void* d_ws, size_t ws_size,
                              hipStream_t stream) {
    const float* x        = (const float*)d_in[0];
    const float* norm_w   = (const float*)d_in[1];
    const float* norm_b   = (const float*)d_in[2];
    const float* in_w     = (const float*)d_in[3];
    const float* in_b     = (const float*)d_in[4];
    const float* conv_w   = (const float*)d_in[5];
    const float* conv_b   = (const float*)d_in[6];
    const float* gih_w    = (const float*)d_in[7];
    const float* ghh_w    = (const float*)d_in[8];
    const float* gih_b    = (const float*)d_in[9];
    const float* ghh_b    = (const float*)d_in[10];
    const float* ssm_w    = (const float*)d_in[11];
    const float* ssm_b    = (const float*)d_in[12];
    const float* out_w    = (const float*)d_in[13];
    const float* out_b    = (const float*)d_in[14];
    float* out = (float*)d_out;

    char* w = (char*)d_ws;
    unsigned short* xn = (unsigned short*)(w);                         // T*512*2   = 16,777,216
    unsigned short* xz = (unsigned short*)(w + 16777216);              // T*2048*2  = 67,108,864
    unsigned short* xs = (unsigned short*)(w + 16777216 + 67108864);   // T*1024*2  = 33,554,432
    float*          xg = (float*)(w + 117440512);                      // [8][48][2048] f32 = 3,145,728
    float*          yb = (float*)(w + 120586240);                      // [8][16][2048] f32 = 1,048,576

    // 1. LayerNorm -> xn (bf16)
    ln_kernel<<<T_, 64, 0, stream>>>(x, norm_w, norm_b, xn);
    // 2. in_proj: xz[T,2048] = xn @ in_w^T + in_b   (bf16 out)
    gemm_bt<0><<<dim3(2048/64, T_/64), 256, 0, stream>>>(xn, DM, in_w, 2*DI, DM, in_b, nullptr, xz, 2*DI);
    // 3. depthwise conv3 + SiLU -> xs (bf16)
    conv_silu_kernel<<<T_, 256, 0, stream>>>(xz, conv_w, conv_b, xs);
    // 4. xgT[8][48][2048] = (xs @ gih_w^T + gih_b)^T   (transposed f32 out)
    gemm_bt<3><<<dim3(1, T_/64), 256, 0, stream>>>(xs, DI, gih_w, 48, DI, gih_b, nullptr, xg, 48);
    // 5. GRU scan -> yT[8][16][2048]
    gru_kernel<<<1, 128, 0, stream>>>(xg, ghh_w, ghh_b, yb);
    // 6. g = (yT @ ssm_w^T + ssm_b) * silu(z) -> bf16 into xz cols [0,1024)
    gated_kernel<<<T_, 256, 0, stream>>>(yb, ssm_w, ssm_b, xz);
    // 7. out = x + out_b + g @ out_w^T
    gemm_bt<2><<<dim3(DM/64, T_/64), 256, 0, stream>>>(xz, 2*DI, out_w, DM, DI, out_b, x, out, DM);
}

// Round 6
// 806.855 us; speedup vs baseline: 2.4794x; 1.6651x over previous
//
#include <hip/hip_runtime.h>
#include <hip/hip_bf16.h>

#define B_  8
#define L_  2048
#define DM  512
#define DI  1024
#define T_  (B_*L_)        // 16384 tokens
#define EPSF 1e-5f

typedef short v8s __attribute__((ext_vector_type(8)));   // 8 bf16 (guide-verified operand type)
typedef float v4f __attribute__((ext_vector_type(4)));

__device__ __forceinline__ float bf2f(unsigned short h){
    union { unsigned int u; float f; } v; v.u = ((unsigned int)h) << 16; return v.f;
}
__device__ __forceinline__ unsigned short f2bf(float f){
    union { float f; unsigned int u; } v; v.f = f;
    unsigned int r = v.u + 0x7fffu + ((v.u >> 16) & 1u);   // round-nearest-even
    return (unsigned short)(r >> 16);
}
__device__ __forceinline__ float sigmoidf_(float x){ return 1.f/(1.f+__expf(-x)); }

// DPP row-rotate (within 16-lane rows); CTRL: row_ror:N = 0x120+N
template<int CTRL>
__device__ __forceinline__ float dpp_rot(float x){
    int xi = __builtin_bit_cast(int, x);
    int r = __builtin_amdgcn_update_dpp(xi, xi, CTRL, 0xf, 0xf, false);
    return __builtin_bit_cast(float, r);
}

// ---------------------------------------------------------------- f32 -> bf16 (weights)
__global__ void cvt_bf16_kernel(const float* __restrict__ in, unsigned short* __restrict__ out){
    int i = (blockIdx.x*256 + threadIdx.x)*4;
    float4 f = *reinterpret_cast<const float4*>(in + i);
    unsigned int p0 = f2bf(f.x) | ((unsigned int)f2bf(f.y)<<16);
    unsigned int p1 = f2bf(f.z) | ((unsigned int)f2bf(f.w)<<16);
    uint2 pk = {p0,p1};
    *reinterpret_cast<uint2*>(out + i) = pk;
}

// ---------------------------------------------------------------- LayerNorm
__global__ void ln_kernel(const float* __restrict__ x, const float* __restrict__ w,
                          const float* __restrict__ b, unsigned short* __restrict__ xn){
    int row = blockIdx.x;
    int lane = threadIdx.x;                       // 0..63
    const float* xr = x + (size_t)row*DM;
    float v[8]; float s = 0.f, sq = 0.f;
    #pragma unroll
    for(int j=0;j<8;j++){ v[j] = xr[lane + 64*j]; s += v[j]; sq += v[j]*v[j]; }
    #pragma unroll
    for(int o=32;o>0;o>>=1){ s += __shfl_xor(s,o); sq += __shfl_xor(sq,o); }
    float mu  = s*(1.f/DM);
    float var = sq*(1.f/DM) - mu*mu;
    float rs  = rsqrtf(var + EPSF);
    unsigned short* out = xn + (size_t)row*DM;
    #pragma unroll
    for(int j=0;j<8;j++){
        int c = lane + 64*j;
        out[c] = f2bf((v[j]-mu)*rs*w[c] + b[c]);
    }
}

// ---------------------------------------------------------------- MFMA GEMM
// C[M,N] = A(bf16,[M,K],lda) * Bw(bf16,[N,K])^T + bias
// 128x128 tile, BK=64, 4 waves (each 64x64 = 4x4 frags of 16x16x32).
// OUTMODE 0: bf16 store (ldc);  2: f32 store + bias + residual (ldc)
template<int OUTMODE>
__global__ __launch_bounds__(256) void gemm_mfma(
    const unsigned short* __restrict__ A, int lda,
    const unsigned short* __restrict__ Bw, int K,
    const float* __restrict__ bias,
    const float* __restrict__ resid,
    void* __restrict__ Cout, int ldc)
{
    __shared__ __align__(16) unsigned short As[128][72];   // +8 pad: b128 reads 2-way (free)
    __shared__ __align__(16) unsigned short Bs[128][72];
    const int m0 = blockIdx.y * 128;
    const int n0 = blockIdx.x * 128;
    const int tid = threadIdx.x;
    const int wave = tid >> 6;
    const int lane = tid & 63;
    const int wm = (wave >> 1) * 64, wn = (wave & 1) * 64;
    const int r16 = lane & 15, kc = lane >> 4;     // frag row/col, k-chunk

    const int srow = tid >> 3;                     // staging: 0..31
    const int scol = (tid & 7) * 8;                // 0,8,...,56

    v4f acc[4][4];
    #pragma unroll
    for(int i=0;i<4;i++)
        #pragma unroll
        for(int j=0;j<4;j++) acc[i][j] = (v4f){0.f,0.f,0.f,0.f};

    for(int k0=0;k0<K;k0+=64){
        #pragma unroll
        for(int p=0;p<4;p++){
            int rr = srow + p*32;
            uint4 av = *reinterpret_cast<const uint4*>(A  + (size_t)(m0+rr)*lda + k0 + scol);
            uint4 bv = *reinterpret_cast<const uint4*>(Bw + (size_t)(n0+rr)*K   + k0 + scol);
            *reinterpret_cast<uint4*>(&As[rr][scol]) = av;
            *reinterpret_cast<uint4*>(&Bs[rr][scol]) = bv;
        }
        __syncthreads();
        #pragma unroll
        for(int kk=0;kk<2;kk++){
            v8s af[4], bfr[4];
            #pragma unroll
            for(int i=0;i<4;i++)
                af[i] = *reinterpret_cast<const v8s*>(&As[wm + i*16 + r16][kk*32 + kc*8]);
            #pragma unroll
            for(int j=0;j<4;j++)
                bfr[j] = *reinterpret_cast<const v8s*>(&Bs[wn + j*16 + r16][kk*32 + kc*8]);
            #pragma unroll
            for(int i=0;i<4;i++)
                #pragma unroll
                for(int j=0;j<4;j++)
                    acc[i][j] = __builtin_amdgcn_mfma_f32_16x16x32_bf16(af[i], bfr[j], acc[i][j], 0, 0, 0);
        }
        __syncthreads();
    }

    // epilogue: C row = m0+wm+i*16+kc*4+r, col = n0+wn+j*16+r16
    #pragma unroll
    for(int j=0;j<4;j++){
        int col = n0 + wn + j*16 + r16;
        float bj = bias[col];
        #pragma unroll
        for(int i=0;i<4;i++){
            int rowb = m0 + wm + i*16 + kc*4;
            #pragma unroll
            for(int r=0;r<4;r++){
                size_t row = (size_t)(rowb + r);
                float v = acc[i][j][r] + bj;
                if(OUTMODE == 0){
                    ((unsigned short*)Cout)[row*ldc + col] = f2bf(v);
                } else {
                    ((float*)Cout)[row*ldc + col] = v + resid[row*ldc + col];
                }
            }
        }
    }
}

// ---------------------------------------------------------------- SIMT GEMM (xg only): C^T = (A @ Bw^T + bias), transposed store [8][N][2048]
__global__ void gemm_bt3(const unsigned short* __restrict__ A, int lda,
                         const float* __restrict__ Bw, int N, int K,
                         const float* __restrict__ bias,
                         float* __restrict__ Cout)
{
    __shared__ __align__(16) float Ast[32][68];   // k-major, padded
    __shared__ __align__(16) float Bst[32][68];
    const int m0 = blockIdx.y * 64;
    const int tid = threadIdx.x;
    const int ty = tid >> 4, tx = tid & 15;
    const int lrow = tid >> 2;
    const int lkb  = (tid & 3) * 8;
    float acc[4][4] = {{0.f}};

    for(int k0 = 0; k0 < K; k0 += 32){
        {
            const unsigned short* ap = A + (size_t)(m0+lrow)*lda + k0 + lkb;
            uint4 pk = *reinterpret_cast<const uint4*>(ap);
            unsigned int uu[4] = {pk.x, pk.y, pk.z, pk.w};
            #pragma unroll
            for(int j=0;j<4;j++){
                Ast[lkb+2*j  ][lrow] = bf2f((unsigned short)(uu[j] & 0xffffu));
                Ast[lkb+2*j+1][lrow] = bf2f((unsigned short)(uu[j] >> 16));
            }
        }
        {
            int n = lrow;
            float4 f0 = {0,0,0,0}, f1 = {0,0,0,0};
            if(n < N){
                const float* bp = Bw + (size_t)n*K + k0 + lkb;
                f0 = *reinterpret_cast<const float4*>(bp);
                f1 = *reinterpret_cast<const float4*>(bp+4);
            }
            Bst[lkb+0][lrow]=f0.x; Bst[lkb+1][lrow]=f0.y; Bst[lkb+2][lrow]=f0.z; Bst[lkb+3][lrow]=f0.w;
            Bst[lkb+4][lrow]=f1.x; Bst[lkb+5][lrow]=f1.y; Bst[lkb+6][lrow]=f1.z; Bst[lkb+7][lrow]=f1.w;
        }
        __syncthreads();
        #pragma unroll
        for(int kk=0;kk<32;kk++){
            float4 a4 = *reinterpret_cast<const float4*>(&Ast[kk][ty*4]);
            float4 b4 = *reinterpret_cast<const float4*>(&Bst[kk][tx*4]);
            float av[4] = {a4.x,a4.y,a4.z,a4.w};
            float bv[4] = {b4.x,b4.y,b4.z,b4.w};
            #pragma unroll
            for(int i=0;i<4;i++)
                #pragma unroll
                for(int j=0;j<4;j++)
                    acc[i][j] += av[i]*bv[j];
        }
        __syncthreads();
    }
    #pragma unroll
    for(int i=0;i<4;i++){
        size_t r = (size_t)(m0 + ty*4 + i);
        size_t bb = r >> 11, ll = r & 2047;
        int c = tx*4;
        #pragma unroll
        for(int j=0;j<4;j++){
            int cc = c + j;
            if(cc < N) Cout[(bb*(size_t)N + cc)*2048 + ll] = acc[i][j] + bias[cc];
        }
    }
}

// ---------------------------------------------------------------- depthwise conv3 + SiLU
__global__ void conv_silu_kernel(const unsigned short* __restrict__ xz,
                                 const float* __restrict__ cw, const float* __restrict__ cb,
                                 unsigned short* __restrict__ xs){
    int t = blockIdx.x;
    int l = t & (L_-1);
    int c = threadIdx.x * 4;
    const unsigned short* row = xz + (size_t)t*2048 + c;
    float cur[4], prv[4]={0,0,0,0}, nxt[4]={0,0,0,0};
    {
        uint2 u = *reinterpret_cast<const uint2*>(row);
        cur[0]=bf2f(u.x&0xffffu); cur[1]=bf2f(u.x>>16); cur[2]=bf2f(u.y&0xffffu); cur[3]=bf2f(u.y>>16);
    }
    if(l > 0){
        uint2 u = *reinterpret_cast<const uint2*>(row - 2048);
        prv[0]=bf2f(u.x&0xffffu); prv[1]=bf2f(u.x>>16); prv[2]=bf2f(u.y&0xffffu); prv[3]=bf2f(u.y>>16);
    }
    if(l < L_-1){
        uint2 u = *reinterpret_cast<const uint2*>(row + 2048);
        nxt[0]=bf2f(u.x&0xffffu); nxt[1]=bf2f(u.x>>16); nxt[2]=bf2f(u.y&0xffffu); nxt[3]=bf2f(u.y>>16);
    }
    unsigned short o[4];
    #pragma unroll
    for(int j=0;j<4;j++){
        int ch = c + j;
        float v = cw[ch*3+0]*prv[j] + cw[ch*3+1]*cur[j] + cw[ch*3+2]*nxt[j] + cb[ch];
        o[j] = f2bf(v * sigmoidf_(v));
    }
    unsigned int p0 = o[0] | ((unsigned int)o[1]<<16);
    unsigned int p1 = o[2] | ((unsigned int)o[3]<<16);
    uint2 pk = {p0,p1};
    *reinterpret_cast<uint2*>(xs + (size_t)t*1024 + c) = pk;
}

// ---------------------------------------------------------------- GRU scan (serial over L) — unchanged from R4
__global__ void gru_kernel(const float* __restrict__ xgT, const float* __restrict__ whh,
                           const float* __restrict__ bhh, float* __restrict__ yT){
    int tid = threadIdx.x;
    int b = tid >> 4, s = tid & 15;
    int mk = __builtin_amdgcn_update_dpp(s, s, 0x121, 0xf, 0xf, false);
    int dir = (mk == ((s+15)&15)) ? 15 : 1;      // 15 ≡ -1 (mod 16)
    float wr[2][8], wz[2][8], wn[2][8];
    #pragma unroll
    for(int m=0;m<8;m++){
        int jA = (s + 2*m*dir) & 15;
        int jB = (s + (2*m+1)*dir) & 15;
        wr[0][m] = whh[(     s)*16 + jA]; wr[1][m] = whh[(     s)*16 + jB];
        wz[0][m] = whh[(16 + s)*16 + jA]; wz[1][m] = whh[(16 + s)*16 + jB];
        wn[0][m] = whh[(32 + s)*16 + jA]; wn[1][m] = whh[(32 + s)*16 + jB];
    }
    float br = bhh[s], bz = bhh[16+s], bn = bhh[32+s];
    const float* xr_ = xgT + ((size_t)b*48 +      s)*L_;
    const float* xz_ = xgT + ((size_t)b*48 + 16 + s)*L_;
    const float* xn_ = xgT + ((size_t)b*48 + 32 + s)*L_;
    float* yp = yT + ((size_t)b*16 + s)*L_;

    union F4 { float4 v; float a[4]; };
    F4 fr[4], fz[4], fn[4];
    #pragma unroll
    for(int g=0; g<4; g++){
        fr[g].v = *reinterpret_cast<const float4*>(xr_ + g*4);
        fz[g].v = *reinterpret_cast<const float4*>(xz_ + g*4);
        fn[g].v = *reinterpret_cast<const float4*>(xn_ + g*4);
    }
    float hself = 0.f;
    for(int tg=0; tg<512; tg+=4){
        #pragma unroll
        for(int q=0;q<4;q++){
            int nx = tg + q + 4; if(nx > 511) nx = 511;
            float4 pr = *reinterpret_cast<const float4*>(xr_ + nx*4);
            float4 pz = *reinterpret_cast<const float4*>(xz_ + nx*4);
            float4 pn = *reinterpret_cast<const float4*>(xn_ + nx*4);
            F4 ho;
            #pragma unroll
            for(int j=0;j<4;j++){
                float hrA = hself;
                float hrB = dpp_rot<0x121>(hself);    // ror:1
                float grA=0.f,gzA=0.f,gnA=0.f, grB=0.f,gzB=0.f,gnB=0.f;
                #pragma unroll
                for(int m=0;m<8;m++){
                    grA += wr[0][m]*hrA; gzA += wz[0][m]*hrA; gnA += wn[0][m]*hrA;
                    grB += wr[1][m]*hrB; gzB += wz[1][m]*hrB; gnB += wn[1][m]*hrB;
                    if(m<7){ hrA = dpp_rot<0x122>(hrA); hrB = dpp_rot<0x122>(hrB); }  // ror:2
                }
                float r   = sigmoidf_(fr[q].a[j] + br + grA + grB);
                float zt  = sigmoidf_(fz[q].a[j] + bz + gzA + gzB);
                float gn  = bn + gnA + gnB;
                float pre = fn[q].a[j] + r*gn;
                float n   = 2.f*sigmoidf_(2.f*pre) - 1.f;    // tanh
                hself = (1.f - zt)*n + zt*hself;
                ho.a[j] = hself;
            }
            *reinterpret_cast<float4*>(yp + (size_t)(tg+q)*4) = ho.v;
            fr[q].v = pr; fz[q].v = pz; fn[q].v = pn;
        }
    }
}

// ---------------------------------------------------------------- ssm_proj + gate
__global__ void gated_kernel(const float* __restrict__ yT, const float* __restrict__ sw,
                             const float* __restrict__ sb, unsigned short* __restrict__ xz){
    int t = blockIdx.x;
    int bb = t >> 11, ll = t & 2047;
    __shared__ float ys[16];
    if(threadIdx.x < 16) ys[threadIdx.x] = yT[((size_t)bb*16 + threadIdx.x)*L_ + ll];
    __syncthreads();
    int e = threadIdx.x * 4;
    uint2 zz = *reinterpret_cast<const uint2*>(xz + (size_t)t*2048 + 1024 + e);
    float zv[4] = {bf2f(zz.x&0xffffu), bf2f(zz.x>>16), bf2f(zz.y&0xffffu), bf2f(zz.y>>16)};
    unsigned short o[4];
    #pragma unroll
    for(int j=0;j<4;j++){
        const float* wrow = sw + (size_t)(e+j)*16;
        float a = sb[e+j];
        #pragma unroll
        for(int k=0;k<16;k++) a += wrow[k]*ys[k];
        float sz = zv[j]*sigmoidf_(zv[j]);
        o[j] = f2bf(a*sz);
    }
    unsigned int p0 = o[0] | ((unsigned int)o[1]<<16);
    unsigned int p1 = o[2] | ((unsigned int)o[3]<<16);
    uint2 pk = {p0,p1};
    *reinterpret_cast<uint2*>(xz + (size_t)t*2048 + e) = pk;
}

// ---------------------------------------------------------------- launcher
extern "C" void kernel_launch(void* const* d_in, const int* in_sizes, int n_in,
                              void* d_out, int out_size, void* d_ws, size_t ws_size,
                              hipStream_t stream) {
    const float* x        = (const float*)d_in[0];
    const float* norm_w   = (const float*)d_in[1];
    const float* norm_b   = (const float*)d_in[2];
    const float* in_w     = (const float*)d_in[3];
    const float* in_b     = (const float*)d_in[4];
    const float* conv_w   = (const float*)d_in[5];
    const float* conv_b   = (const float*)d_in[6];
    const float* gih_w    = (const float*)d_in[7];
    const float* ghh_w    = (const float*)d_in[8];
    const float* gih_b    = (const float*)d_in[9];
    const float* ghh_b    = (const float*)d_in[10];
    const float* ssm_w    = (const float*)d_in[11];
    const float* ssm_b    = (const float*)d_in[12];
    const float* out_w    = (const float*)d_in[13];
    const float* out_b    = (const float*)d_in[14];
    float* out = (float*)d_out;

    char* w = (char*)d_ws;
    unsigned short* xn    = (unsigned short*)(w);                       // T*512*2   = 16,777,216
    unsigned short* xz    = (unsigned short*)(w + 16777216);            // T*2048*2  = 67,108,864
    unsigned short* xs    = (unsigned short*)(w + 16777216 + 67108864); // T*1024*2  = 33,554,432
    float*          xg    = (float*)(w + 117440512);                    // [8][48][2048] f32 = 3,145,728
    float*          yb    = (float*)(w + 120586240);                    // [8][16][2048] f32 = 1,048,576
    unsigned short* in_wb = (unsigned short*)(w + 121634816);           // 2048*512 bf16 = 2,097,152
    unsigned short* out_wb= (unsigned short*)(w + 123731968);           // 512*1024 bf16 = 1,048,576

    // 0. weight conversion f32 -> bf16
    cvt_bf16_kernel<<<(2*DI*DM)/1024, 256, 0, stream>>>(in_w, in_wb);
    cvt_bf16_kernel<<<(DM*DI)/1024, 256, 0, stream>>>(out_w, out_wb);
    // 1. LayerNorm -> xn (bf16)
    ln_kernel<<<T_, 64, 0, stream>>>(x, norm_w, norm_b, xn);
    // 2. in_proj (MFMA): xz[T,2048] = xn @ in_wb^T + in_b   (bf16 out)
    gemm_mfma<0><<<dim3(2048/128, T_/128), 256, 0, stream>>>(xn, DM, in_wb, DM, in_b, nullptr, xz, 2*DI);
    // 3. depthwise conv3 + SiLU -> xs (bf16)
    conv_silu_kernel<<<T_, 256, 0, stream>>>(xz, conv_w, conv_b, xs);
    // 4. xgT[8][48][2048] = (xs @ gih_w^T + gih_b)^T   (SIMT, transposed f32 out)
    gemm_bt3<<<dim3(1, T_/64), 256, 0, stream>>>(xs, DI, gih_w, 48, DI, gih_b, xg);
    // 5. GRU scan -> yT[8][16][2048]
    gru_kernel<<<1, 128, 0, stream>>>(xg, ghh_w, ghh_b, yb);
    // 6. g = (yT @ ssm_w^T + ssm_b) * silu(z) -> bf16 into xz cols [0,1024)
    gated_kernel<<<T_, 256, 0, stream>>>(yb, ssm_w, ssm_b, xz);
    // 7. out (MFMA): out = x + out_b + g @ out_wb^T
    gemm_mfma<2><<<dim3(DM/128, T_/128), 256, 0, stream>>>(xz, 2*DI, out_wb, DI, out_b, x, out, DM);
}

// Round 7
// 659.196 us; speedup vs baseline: 3.0348x; 1.2240x over previous
//
#include <hip/hip_runtime.h>
#include <hip/hip_bf16.h>

#define B_  8
#define L_  2048
#define DM  512
#define DI  1024
#define T_  (B_*L_)        // 16384 tokens
#define EPSF 1e-5f

typedef short v8s __attribute__((ext_vector_type(8)));   // 8 bf16 (guide-verified operand type)
typedef float v4f __attribute__((ext_vector_type(4)));

__device__ __forceinline__ float bf2f(unsigned short h){
    union { unsigned int u; float f; } v; v.u = ((unsigned int)h) << 16; return v.f;
}
__device__ __forceinline__ unsigned short f2bf(float f){
    union { float f; unsigned int u; } v; v.f = f;
    unsigned int r = v.u + 0x7fffu + ((v.u >> 16) & 1u);   // round-nearest-even
    return (unsigned short)(r >> 16);
}
__device__ __forceinline__ float sigmoidf_(float x){ return 1.f/(1.f+__expf(-x)); }
// fast gates: v_exp_f32 is 2^x; v_rcp_f32 ~1ulp
__device__ __forceinline__ float sig_fast(float x){
    float e = __builtin_amdgcn_exp2f(x * -1.44269504089f);
    return __builtin_amdgcn_rcpf(1.f + e);
}
__device__ __forceinline__ float tanh_fast(float x){
    float e = __builtin_amdgcn_exp2f(x * -2.88539008178f);
    return __builtin_fmaf(2.f, __builtin_amdgcn_rcpf(1.f + e), -1.f);
}

// DPP row-rotate (within 16-lane rows); CTRL: row_ror:N = 0x120+N
template<int CTRL>
__device__ __forceinline__ float dpp_rot(float x){
    int xi = __builtin_bit_cast(int, x);
    int r = __builtin_amdgcn_update_dpp(xi, xi, CTRL, 0xf, 0xf, false);
    return __builtin_bit_cast(float, r);
}

// partner value across lane (l xor 32): VALU permlane if available, else shfl
__device__ __forceinline__ float xor32_val(float x, int l){
#if __has_builtin(__builtin_amdgcn_permlane32_swap)
    typedef int v2i __attribute__((ext_vector_type(2)));
    int xi = __builtin_bit_cast(int, x);
    v2i r = __builtin_amdgcn_permlane32_swap(xi, xi, false, false);
    int p = (l < 32) ? r.x : r.y;
    return __builtin_bit_cast(float, p);
#else
    return __shfl_xor(x, 32, 64);
#endif
}

// ---------------------------------------------------------------- f32 -> bf16 (weights)
__global__ void cvt_bf16_kernel(const float* __restrict__ in, unsigned short* __restrict__ out){
    int i = (blockIdx.x*256 + threadIdx.x)*4;
    float4 f = *reinterpret_cast<const float4*>(in + i);
    unsigned int p0 = f2bf(f.x) | ((unsigned int)f2bf(f.y)<<16);
    unsigned int p1 = f2bf(f.z) | ((unsigned int)f2bf(f.w)<<16);
    uint2 pk = {p0,p1};
    *reinterpret_cast<uint2*>(out + i) = pk;
}

// ---------------------------------------------------------------- LayerNorm
__global__ void ln_kernel(const float* __restrict__ x, const float* __restrict__ w,
                          const float* __restrict__ b, unsigned short* __restrict__ xn){
    int row = blockIdx.x;
    int lane = threadIdx.x;                       // 0..63
    const float* xr = x + (size_t)row*DM;
    float v[8]; float s = 0.f, sq = 0.f;
    #pragma unroll
    for(int j=0;j<8;j++){ v[j] = xr[lane + 64*j]; s += v[j]; sq += v[j]*v[j]; }
    #pragma unroll
    for(int o=32;o>0;o>>=1){ s += __shfl_xor(s,o); sq += __shfl_xor(sq,o); }
    float mu  = s*(1.f/DM);
    float var = sq*(1.f/DM) - mu*mu;
    float rs  = rsqrtf(var + EPSF);
    unsigned short* out = xn + (size_t)row*DM;
    #pragma unroll
    for(int j=0;j<8;j++){
        int c = lane + 64*j;
        out[c] = f2bf((v[j]-mu)*rs*w[c] + b[c]);
    }
}

// ---------------------------------------------------------------- MFMA GEMM (unchanged from R5)
template<int OUTMODE>
__global__ __launch_bounds__(256) void gemm_mfma(
    const unsigned short* __restrict__ A, int lda,
    const unsigned short* __restrict__ Bw, int K,
    const float* __restrict__ bias,
    const float* __restrict__ resid,
    void* __restrict__ Cout, int ldc)
{
    __shared__ __align__(16) unsigned short As[128][72];
    __shared__ __align__(16) unsigned short Bs[128][72];
    const int m0 = blockIdx.y * 128;
    const int n0 = blockIdx.x * 128;
    const int tid = threadIdx.x;
    const int wave = tid >> 6;
    const int lane = tid & 63;
    const int wm = (wave >> 1) * 64, wn = (wave & 1) * 64;
    const int r16 = lane & 15, kc = lane >> 4;

    const int srow = tid >> 3;
    const int scol = (tid & 7) * 8;

    v4f acc[4][4];
    #pragma unroll
    for(int i=0;i<4;i++)
        #pragma unroll
        for(int j=0;j<4;j++) acc[i][j] = (v4f){0.f,0.f,0.f,0.f};

    for(int k0=0;k0<K;k0+=64){
        #pragma unroll
        for(int p=0;p<4;p++){
            int rr = srow + p*32;
            uint4 av = *reinterpret_cast<const uint4*>(A  + (size_t)(m0+rr)*lda + k0 + scol);
            uint4 bv = *reinterpret_cast<const uint4*>(Bw + (size_t)(n0+rr)*K   + k0 + scol);
            *reinterpret_cast<uint4*>(&As[rr][scol]) = av;
            *reinterpret_cast<uint4*>(&Bs[rr][scol]) = bv;
        }
        __syncthreads();
        #pragma unroll
        for(int kk=0;kk<2;kk++){
            v8s af[4], bfr[4];
            #pragma unroll
            for(int i=0;i<4;i++)
                af[i] = *reinterpret_cast<const v8s*>(&As[wm + i*16 + r16][kk*32 + kc*8]);
            #pragma unroll
            for(int j=0;j<4;j++)
                bfr[j] = *reinterpret_cast<const v8s*>(&Bs[wn + j*16 + r16][kk*32 + kc*8]);
            #pragma unroll
            for(int i=0;i<4;i++)
                #pragma unroll
                for(int j=0;j<4;j++)
                    acc[i][j] = __builtin_amdgcn_mfma_f32_16x16x32_bf16(af[i], bfr[j], acc[i][j], 0, 0, 0);
        }
        __syncthreads();
    }

    #pragma unroll
    for(int j=0;j<4;j++){
        int col = n0 + wn + j*16 + r16;
        float bj = bias[col];
        #pragma unroll
        for(int i=0;i<4;i++){
            int rowb = m0 + wm + i*16 + kc*4;
            #pragma unroll
            for(int r=0;r<4;r++){
                size_t row = (size_t)(rowb + r);
                float v = acc[i][j][r] + bj;
                if(OUTMODE == 0){
                    ((unsigned short*)Cout)[row*ldc + col] = f2bf(v);
                } else {
                    ((float*)Cout)[row*ldc + col] = v + resid[row*ldc + col];
                }
            }
        }
    }
}

// ---------------------------------------------------------------- SIMT GEMM (xg): transposed store [8][48][2048]
__global__ void gemm_bt3(const unsigned short* __restrict__ A, int lda,
                         const float* __restrict__ Bw, int N, int K,
                         const float* __restrict__ bias,
                         float* __restrict__ Cout)
{
    __shared__ __align__(16) float Ast[32][68];
    __shared__ __align__(16) float Bst[32][68];
    const int m0 = blockIdx.y * 64;
    const int tid = threadIdx.x;
    const int ty = tid >> 4, tx = tid & 15;
    const int lrow = tid >> 2;
    const int lkb  = (tid & 3) * 8;
    float acc[4][4] = {{0.f}};

    for(int k0 = 0; k0 < K; k0 += 32){
        {
            const unsigned short* ap = A + (size_t)(m0+lrow)*lda + k0 + lkb;
            uint4 pk = *reinterpret_cast<const uint4*>(ap);
            unsigned int uu[4] = {pk.x, pk.y, pk.z, pk.w};
            #pragma unroll
            for(int j=0;j<4;j++){
                Ast[lkb+2*j  ][lrow] = bf2f((unsigned short)(uu[j] & 0xffffu));
                Ast[lkb+2*j+1][lrow] = bf2f((unsigned short)(uu[j] >> 16));
            }
        }
        {
            int n = lrow;
            float4 f0 = {0,0,0,0}, f1 = {0,0,0,0};
            if(n < N){
                const float* bp = Bw + (size_t)n*K + k0 + lkb;
                f0 = *reinterpret_cast<const float4*>(bp);
                f1 = *reinterpret_cast<const float4*>(bp+4);
            }
            Bst[lkb+0][lrow]=f0.x; Bst[lkb+1][lrow]=f0.y; Bst[lkb+2][lrow]=f0.z; Bst[lkb+3][lrow]=f0.w;
            Bst[lkb+4][lrow]=f1.x; Bst[lkb+5][lrow]=f1.y; Bst[lkb+6][lrow]=f1.z; Bst[lkb+7][lrow]=f1.w;
        }
        __syncthreads();
        #pragma unroll
        for(int kk=0;kk<32;kk++){
            float4 a4 = *reinterpret_cast<const float4*>(&Ast[kk][ty*4]);
            float4 b4 = *reinterpret_cast<const float4*>(&Bst[kk][tx*4]);
            float av[4] = {a4.x,a4.y,a4.z,a4.w};
            float bv[4] = {b4.x,b4.y,b4.z,b4.w};
            #pragma unroll
            for(int i=0;i<4;i++)
                #pragma unroll
                for(int j=0;j<4;j++)
                    acc[i][j] += av[i]*bv[j];
        }
        __syncthreads();
    }
    #pragma unroll
    for(int i=0;i<4;i++){
        size_t r = (size_t)(m0 + ty*4 + i);
        size_t bb = r >> 11, ll = r & 2047;
        int c = tx*4;
        #pragma unroll
        for(int j=0;j<4;j++){
            int cc = c + j;
            if(cc < N) Cout[(bb*(size_t)N + cc)*2048 + ll] = acc[i][j] + bias[cc];
        }
    }
}

// ---------------------------------------------------------------- depthwise conv3 + SiLU
__global__ void conv_silu_kernel(const unsigned short* __restrict__ xz,
                                 const float* __restrict__ cw, const float* __restrict__ cb,
                                 unsigned short* __restrict__ xs){
    int t = blockIdx.x;
    int l = t & (L_-1);
    int c = threadIdx.x * 4;
    const unsigned short* row = xz + (size_t)t*2048 + c;
    float cur[4], prv[4]={0,0,0,0}, nxt[4]={0,0,0,0};
    {
        uint2 u = *reinterpret_cast<const uint2*>(row);
        cur[0]=bf2f(u.x&0xffffu); cur[1]=bf2f(u.x>>16); cur[2]=bf2f(u.y&0xffffu); cur[3]=bf2f(u.y>>16);
    }
    if(l > 0){
        uint2 u = *reinterpret_cast<const uint2*>(row - 2048);
        prv[0]=bf2f(u.x&0xffffu); prv[1]=bf2f(u.x>>16); prv[2]=bf2f(u.y&0xffffu); prv[3]=bf2f(u.y>>16);
    }
    if(l < L_-1){
        uint2 u = *reinterpret_cast<const uint2*>(row + 2048);
        nxt[0]=bf2f(u.x&0xffffu); nxt[1]=bf2f(u.x>>16); nxt[2]=bf2f(u.y&0xffffu); nxt[3]=bf2f(u.y>>16);
    }
    unsigned short o[4];
    #pragma unroll
    for(int j=0;j<4;j++){
        int ch = c + j;
        float v = cw[ch*3+0]*prv[j] + cw[ch*3+1]*cur[j] + cw[ch*3+2]*nxt[j] + cb[ch];
        o[j] = f2bf(v * sigmoidf_(v));
    }
    unsigned int p0 = o[0] | ((unsigned int)o[1]<<16);
    unsigned int p1 = o[2] | ((unsigned int)o[3]<<16);
    uint2 pk = {p0,p1};
    *reinterpret_cast<uint2*>(xs + (size_t)t*1024 + c) = pk;
}

// ---------------------------------------------------------------- GRU scan v3
// 256 threads = 4 waves, 1 block. Wave layout (l = tid&63):
//   row0 (l 0-15):  batch 2w+0, half 0     row1 (l 16-31): batch 2w+1, half 0
//   row2 (l 32-47): batch 2w+0, half 1     row3 (l 48-63): batch 2w+1, half 1
// Lane (b,s,half) holds h[s]; each half accumulates 8 of 16 k's via two
// 4-deep ror:2 DPP chains (half1 offset by ror:8 prologue, cndmask-selected).
// Halves combined with permlane32_swap (VALU). Gates replicated on all lanes.
// y staged in LDS (lgkm counter) and bulk-flushed every 64 steps, keeping the
// global-load vmcnt stream pure so the 16-step prefetch pipeline never drains.
__global__ __launch_bounds__(256) void gru_kernel(
    const float* __restrict__ xgT, const float* __restrict__ whh,
    const float* __restrict__ bhh, float* __restrict__ yT){
    __shared__ __align__(16) float ystage[8][16][68];   // 34.8 KB, padded
    const int tid = threadIdx.x;
    const int l = tid & 63;
    const int s = l & 15;
    const int half = l >> 5;
    const int b = (tid >> 6)*2 + ((l >> 4) & 1);

    // DPP direction self-check (deterministic)
    int mk = __builtin_amdgcn_update_dpp(s, s, 0x121, 0xf, 0xf, false);
    int dir = (mk == ((s+15)&15)) ? 15 : 1;      // 15 ≡ -1 (mod 16)

    // permuted weights: chain A position m sees h[(s + (8*half + 2m)*dir)&15],
    // chain B sees h[(s + (8*half + 2m+1)*dir)&15]
    float wr[2][4], wz[2][4], wn[2][4];
    #pragma unroll
    for(int m=0;m<4;m++){
        int jA = (s + (8*half + 2*m    )*dir) & 15;
        int jB = (s + (8*half + 2*m + 1)*dir) & 15;
        wr[0][m] = whh[(     s)*16 + jA]; wr[1][m] = whh[(     s)*16 + jB];
        wz[0][m] = whh[(16 + s)*16 + jA]; wz[1][m] = whh[(16 + s)*16 + jB];
        wn[0][m] = whh[(32 + s)*16 + jA]; wn[1][m] = whh[(32 + s)*16 + jB];
    }
    float br = bhh[s], bz = bhh[16+s], bn = bhh[32+s];
    const float* xr_ = xgT + ((size_t)b*48 +      s)*L_;
    const float* xz_ = xgT + ((size_t)b*48 + 16 + s)*L_;
    const float* xn_ = xgT + ((size_t)b*48 + 32 + s)*L_;
    float* yp = yT + ((size_t)b*16 + s)*L_;

    union F4 { float4 v; float a[4]; };
    F4 fr[4], fz[4], fn[4];
    #pragma unroll
    for(int g=0; g<4; g++){
        fr[g].v = *reinterpret_cast<const float4*>(xr_ + g*4);
        fz[g].v = *reinterpret_cast<const float4*>(xz_ + g*4);
        fn[g].v = *reinterpret_cast<const float4*>(xn_ + g*4);
    }
    float hself = 0.f;
    // outer o: 16 steps each; flush every 4 outers (64 steps)
    for(int o=0; o<128; ++o){
        #pragma unroll
        for(int q=0;q<4;q++){
            int G = o*4 + q;                       // 4-step group index
            int nx = G + 4; if(nx > 511) nx = 511; // prefetch distance 16 steps
            float4 pr = *reinterpret_cast<const float4*>(xr_ + nx*4);
            float4 pz = *reinterpret_cast<const float4*>(xz_ + nx*4);
            float4 pn = *reinterpret_cast<const float4*>(xn_ + nx*4);
            F4 ho;
            #pragma unroll
            for(int j=0;j<4;j++){
                // prologue: half1 starts its sweep at ror:8
                float g8  = dpp_rot<0x128>(hself);             // ror:8
                float hrA = half ? g8 : hself;                 // v_cndmask
                float hrB = dpp_rot<0x121>(hrA);               // ror:1
                float grA=0.f,gzA=0.f,gnA=0.f, grB=0.f,gzB=0.f,gnB=0.f;
                #pragma unroll
                for(int m=0;m<4;m++){
                    grA += wr[0][m]*hrA; gzA += wz[0][m]*hrA; gnA += wn[0][m]*hrA;
                    grB += wr[1][m]*hrB; gzB += wz[1][m]*hrB; gnB += wn[1][m]*hrB;
                    if(m<3){ hrA = dpp_rot<0x122>(hrA); hrB = dpp_rot<0x122>(hrB); }  // ror:2
                }
                float grp = grA + grB, gzp = gzA + gzB, gnp = gnA + gnB;
                // combine the two halves (lane xor 32), all lanes get full sums
                float gr = br + grp + xor32_val(grp, l);
                float gz = bz + gzp + xor32_val(gzp, l);
                float gn = bn + gnp + xor32_val(gnp, l);
                float r   = sig_fast(fr[q].a[j] + gr);
                float zt  = sig_fast(fz[q].a[j] + gz);
                float pre = fn[q].a[j] + r*gn;
                float n   = tanh_fast(pre);
                hself = (1.f - zt)*n + zt*hself;
                ho.a[j] = hself;
            }
            if(l < 32){  // half0 lanes own the y write (replicated elsewhere)
                *reinterpret_cast<float4*>(&ystage[b][s][(G & 15)*4]) = ho.v;
            }
            fr[q].v = pr; fz[q].v = pz; fn[q].v = pn;
        }
        if((o & 3) == 3){
            // flush 64 steps of y: ystage[8][16][64] -> yT, cooperative
            __syncthreads();
            int t0 = (o - 3) * 16;
            #pragma unroll
            for(int k=0;k<8;k++){
                int slot = tid + k*256;            // 0..2047 float4 slots
                int row = slot >> 4, c4 = slot & 15;
                float4 v = *reinterpret_cast<const float4*>(&ystage[0][0][0] + (size_t)row*68 + c4*4);
                *reinterpret_cast<float4*>(yT + (size_t)row*L_ + t0 + c4*4) = v;
            }
            __syncthreads();
        }
    }
}

// ---------------------------------------------------------------- ssm_proj + gate
__global__ void gated_kernel(const float* __restrict__ yT, const float* __restrict__ sw,
                             const float* __restrict__ sb, unsigned short* __restrict__ xz){
    int t = blockIdx.x;
    int bb = t >> 11, ll = t & 2047;
    __shared__ float ys[16];
    if(threadIdx.x < 16) ys[threadIdx.x] = yT[((size_t)bb*16 + threadIdx.x)*L_ + ll];
    __syncthreads();
    int e = threadIdx.x * 4;
    uint2 zz = *reinterpret_cast<const uint2*>(xz + (size_t)t*2048 + 1024 + e);
    float zv[4] = {bf2f(zz.x&0xffffu), bf2f(zz.x>>16), bf2f(zz.y&0xffffu), bf2f(zz.y>>16)};
    unsigned short o[4];
    #pragma unroll
    for(int j=0;j<4;j++){
        const float* wrow = sw + (size_t)(e+j)*16;
        float a = sb[e+j];
        #pragma unroll
        for(int k=0;k<16;k++) a += wrow[k]*ys[k];
        float sz = zv[j]*sigmoidf_(zv[j]);
        o[j] = f2bf(a*sz);
    }
    unsigned int p0 = o[0] | ((unsigned int)o[1]<<16);
    unsigned int p1 = o[2] | ((unsigned int)o[3]<<16);
    uint2 pk = {p0,p1};
    *reinterpret_cast<uint2*>(xz + (size_t)t*2048 + e) = pk;
}

// ---------------------------------------------------------------- launcher
extern "C" void kernel_launch(void* const* d_in, const int* in_sizes, int n_in,
                              void* d_out, int out_size, void* d_ws, size_t ws_size,
                              hipStream_t stream) {
    const float* x        = (const float*)d_in[0];
    const float* norm_w   = (const float*)d_in[1];
    const float* norm_b   = (const float*)d_in[2];
    const float* in_w     = (const float*)d_in[3];
    const float* in_b     = (const float*)d_in[4];
    const float* conv_w   = (const float*)d_in[5];
    const float* conv_b   = (const float*)d_in[6];
    const float* gih_w    = (const float*)d_in[7];
    const float* ghh_w    = (const float*)d_in[8];
    const float* gih_b    = (const float*)d_in[9];
    const float* ghh_b    = (const float*)d_in[10];
    const float* ssm_w    = (const float*)d_in[11];
    const float* ssm_b    = (const float*)d_in[12];
    const float* out_w    = (const float*)d_in[13];
    const float* out_b    = (const float*)d_in[14];
    float* out = (float*)d_out;

    char* w = (char*)d_ws;
    unsigned short* xn    = (unsigned short*)(w);                       // T*512*2   = 16,777,216
    unsigned short* xz    = (unsigned short*)(w + 16777216);            // T*2048*2  = 67,108,864
    unsigned short* xs    = (unsigned short*)(w + 16777216 + 67108864); // T*1024*2  = 33,554,432
    float*          xg    = (float*)(w + 117440512);                    // [8][48][2048] f32 = 3,145,728
    float*          yb    = (float*)(w + 120586240);                    // [8][16][2048] f32 = 1,048,576
    unsigned short* in_wb = (unsigned short*)(w + 121634816);           // 2048*512 bf16 = 2,097,152
    unsigned short* out_wb= (unsigned short*)(w + 123731968);           // 512*1024 bf16 = 1,048,576

    // 0. weight conversion f32 -> bf16
    cvt_bf16_kernel<<<(2*DI*DM)/1024, 256, 0, stream>>>(in_w, in_wb);
    cvt_bf16_kernel<<<(DM*DI)/1024, 256, 0, stream>>>(out_w, out_wb);
    // 1. LayerNorm -> xn (bf16)
    ln_kernel<<<T_, 64, 0, stream>>>(x, norm_w, norm_b, xn);
    // 2. in_proj (MFMA): xz[T,2048] = xn @ in_wb^T + in_b   (bf16 out)
    gemm_mfma<0><<<dim3(2048/128, T_/128), 256, 0, stream>>>(xn, DM, in_wb, DM, in_b, nullptr, xz, 2*DI);
    // 3. depthwise conv3 + SiLU -> xs (bf16)
    conv_silu_kernel<<<T_, 256, 0, stream>>>(xz, conv_w, conv_b, xs);
    // 4. xgT[8][48][2048] = (xs @ gih_w^T + gih_b)^T   (SIMT, transposed f32 out)
    gemm_bt3<<<dim3(1, T_/64), 256, 0, stream>>>(xs, DI, gih_w, 48, DI, gih_b, xg);
    // 5. GRU scan -> yT[8][16][2048]
    gru_kernel<<<1, 256, 0, stream>>>(xg, ghh_w, ghh_b, yb);
    // 6. g = (yT @ ssm_w^T + ssm_b) * silu(z) -> bf16 into xz cols [0,1024)
    gated_kernel<<<T_, 256, 0, stream>>>(yb, ssm_w, ssm_b, xz);
    // 7. out (MFMA): out = x + out_b + g @ out_wb^T
    gemm_mfma<2><<<dim3(DM/128, T_/128), 256, 0, stream>>>(xz, 2*DI, out_wb, DI, out_b, x, out, DM);
}